// Round 9
// baseline (556.458 us; speedup 1.0000x reference)
//
#include <hip/hip_runtime.h>
#include <hip/hip_bf16.h>
#include <cmath>

typedef __hip_bfloat16 bf16;
typedef __attribute__((ext_vector_type(4))) float floatx4;
typedef __attribute__((ext_vector_type(8))) short short8;
typedef __attribute__((ext_vector_type(8))) unsigned short ushort8;

__device__ __forceinline__ float bf2f(bf16 v) { return __bfloat162float(v); }
__device__ __forceinline__ bf16 f2bf(float v) { return __float2bfloat16(v); }
__device__ __forceinline__ float bfu2f(unsigned short u) { return __uint_as_float(((unsigned)u) << 16); }
__device__ __forceinline__ unsigned short f2bfu(float v) {
  bf16 h = __float2bfloat16(v);
  return __builtin_bit_cast(unsigned short, h);
}
__device__ __forceinline__ float softplusf(float x) {
  return x > 20.0f ? x : log1pf(expf(x));
}

__device__ __forceinline__ void async16(const void* g, void* l) {
  __builtin_amdgcn_global_load_lds(
      (const __attribute__((address_space(1))) unsigned int*)g,
      (__attribute__((address_space(3))) unsigned int*)l, 16, 0, 0);
}

// ---------------------------------------------------------------------------
// Generic bf16 GEMM: C[m][n] = sum_k A[m][k] * Bt[n][k]  (+ fp32 bias[n])
// 512 threads / 8 waves (4m x 2n).
// SHAPE 0: 256x128 block tile, wave tile 64x64 (4x4 frags, 16 MFMA/step,
//          8 ds_reads -> 0.5 reads/MFMA; 72KB LDS; vmcnt(3): 3 loads/thr).
// SHAPE 1: 128x128 block tile, wave tile 32x64 (2x4 frags; 48KB LDS;
//          vmcnt(2): 2 loads/thr). For M=128 GEMMs + causal skew balance.
// Tri-buffered BK=32, COUNTED vmcnt (T4): at step t issue loads for tile
// t+2, compute tile t, then wait only t+1's loads + raw s_barrier.
// LDS swizzle (both-sides involution): physical 16B chunk c of row r holds
// logical chunk c ^ ((r>>1)&3); staged via pre-swizzled global source col.
// Read side: gph=(fm>>1)&3 == (R>>1)&3 since wr*WTM, wc*64, i*16 = 0 mod 8.
// MODE 0: bf16 out row-major (ldc).   MODE 1: fp32 out (ldc), ACCUM adds.
// MODE 2: bf16 out transposed-batched: out[((m>>11)*1024 + n)*2048 + (m&2047)]
// CAUSAL: k limited to (m_tile+1)*BM; m-tiles issued heavy-first.
// SWZ: flat grid.x = mtiles*ntiles; XCD-banded decode (bid&7 -> m band).
// KSPLIT>1: z = zz*KSPLIT + kc; K is the CHUNK length, kstart = kc*K.
// All K chunks must be multiples of 32.
// ---------------------------------------------------------------------------
template<int SHAPE, int MODE, int CAUSAL, int ACCUM, int SWZ, int KSPLIT = 1>
__global__ __launch_bounds__(512, 2) void gemm_bt(
    const bf16* __restrict__ A, const bf16* __restrict__ Bt,
    const float* __restrict__ bias, void* __restrict__ Cptr,
    int M, int N, int K, int lda, int ldb, int ldc,
    long aoffz, long boffz, long coffz)
{
  constexpr int BM = (SHAPE == 0) ? 256 : 128;
  constexpr int MI = (SHAPE == 0) ? 4 : 2;     // m-frags per wave
  constexpr int WTM = MI * 16;                 // wave tile m-extent
  __shared__ __align__(16) bf16 As[3][BM * 32];
  __shared__ __align__(16) bf16 Bs[3][128 * 32];

  const int tid = threadIdx.x;
  const int lane = tid & 63;
  const int wave = tid >> 6;            // 0..7
  const int wr = wave >> 1, wc = wave & 1;   // 4m x 2n
  const long z = blockIdx.z;
  int kstart = 0;
  long zz = z;
  if (KSPLIT > 1) {
    kstart = (int)(z % KSPLIT) * K;
    zz = z / KSPLIT;
  }
  A += zz * aoffz;
  Bt += zz * boffz;

  int bx, by;
  if (SWZ) {
    const int mtiles = M / BM;
    const int per = mtiles >> 3;          // m-tiles per XCD band
    const int bid = (int)blockIdx.x;
    const int xcd = bid & 7;
    const int slot = bid >> 3;
    by = xcd * per + (slot % per);
    bx = slot / per;
  } else {
    bx = blockIdx.x;
    by = blockIdx.y;
    if (CAUSAL) by = (int)gridDim.y - 1 - by;   // heavy tiles first
  }
  const int m0 = by * BM, n0 = bx * 128;
  int kend = kstart + K;
  if (CAUSAL) {
    int klim = (by + 1) * BM;
    if (klim < kend) kend = klim;
  }

  // Staging offsets. A tile: BM*4 chunks of 16B (1 or 2 per thread);
  // B tile: 512 chunks (1 per thread). chunk ch -> row ch>>2, slot ch&3;
  // source logical chunk = slot ^ ((row>>1)&3).
  const int r0 = tid >> 2, s0 = tid & 3;
  const int sc0 = (s0 ^ ((r0 >> 1) & 3)) * 8;
  const size_t a0 = (size_t)(m0 + r0) * lda + sc0;
  const size_t b0 = (size_t)(n0 + r0) * ldb + sc0;
  size_t a1 = 0;
  if (SHAPE == 0) {
    const int ch1 = tid + 512;
    const int r1 = ch1 >> 2, s1 = ch1 & 3;
    const int sc1 = (s1 ^ ((r1 >> 1) & 3)) * 8;
    a1 = (size_t)(m0 + r1) * lda + sc1;
  }

  floatx4 acc[MI][4] = {};
  const int fm = lane & 15, fq = lane >> 4;
  const int gph = (fm >> 1) & 3;
  const int nt = (kend - kstart) >> 5;

  auto stage = [&](int buf, int t) {
    const int k0 = kstart + t * 32;
    async16(&A[a0 + k0], &As[buf][tid * 8]);
    if constexpr (SHAPE == 0)
      async16(&A[a1 + k0], &As[buf][(tid + 512) * 8]);
    async16(&Bt[b0 + k0], &Bs[buf][tid * 8]);
  };
  auto wait_steady = [&]() {
    if constexpr (SHAPE == 0) asm volatile("s_waitcnt vmcnt(3)" ::: "memory");
    else                      asm volatile("s_waitcnt vmcnt(2)" ::: "memory");
  };

  stage(0, 0);
  if (nt > 1) {
    stage(1, 1);
    wait_steady();
  } else {
    asm volatile("s_waitcnt vmcnt(0)" ::: "memory");
  }
  asm volatile("s_barrier" ::: "memory");

  int bufc = 0;
  for (int t = 0; t < nt; t++) {
    int bufn = bufc + 2; if (bufn >= 3) bufn -= 3;
    if (t + 2 < nt) stage(bufn, t + 2);
    short8 af[MI], bfr[4];
#pragma unroll
    for (int i = 0; i < MI; i++) {
      int R = wr * WTM + i * 16 + fm;
      af[i] = *(const short8*)&As[bufc][R * 32 + ((fq ^ gph) << 3)];
    }
#pragma unroll
    for (int j = 0; j < 4; j++) {
      int R = wc * 64 + j * 16 + fm;
      bfr[j] = *(const short8*)&Bs[bufc][R * 32 + ((fq ^ gph) << 3)];
    }
#pragma unroll
    for (int i = 0; i < MI; i++)
#pragma unroll
      for (int j = 0; j < 4; j++)
        acc[i][j] = __builtin_amdgcn_mfma_f32_16x16x32_bf16(af[i], bfr[j], acc[i][j], 0, 0, 0);
    if (t + 2 < nt) wait_steady();
    else            asm volatile("s_waitcnt vmcnt(0)" ::: "memory");
    asm volatile("s_barrier" ::: "memory");
    bufc++; if (bufc == 3) bufc = 0;
  }

  const int rm0 = (lane >> 4) * 4, cn = lane & 15;
#pragma unroll
  for (int i = 0; i < MI; i++) {
#pragma unroll
    for (int j = 0; j < 4; j++) {
      int nn = n0 + wc * 64 + j * 16 + cn;
      float bv = bias ? bias[nn] : 0.0f;
#pragma unroll
      for (int r = 0; r < 4; r++) {
        int mm = m0 + wr * WTM + i * 16 + rm0 + r;
        float v = acc[i][j][r] + bv;
        if (MODE == 0) {
          ((bf16*)Cptr)[z * coffz + (long)mm * ldc + nn] = f2bf(v);
        } else if (MODE == 1) {
          long idx = z * coffz + (long)mm * ldc + nn;
          float* Cf = (float*)Cptr;
          if (ACCUM) v += Cf[idx];
          Cf[idx] = v;
        } else {
          long idx = ((long)((mm >> 11) * 1024 + nn)) * 2048 + (mm & 2047);
          ((bf16*)Cptr)[idx] = f2bf(v);
        }
      }
    }
  }
}

// ---------------------------------------------------------------------------
// y GEMM: y[t][d] = sum_{k'=0..3071} A'[t][k'] * Bt2[d][k']  + sw-weighted bias
// A' = [sw0*x | sw1*x | sw2*x] bf16, Bt2[d][s*1024+k] = W_sense[k][s*1024+d].
// SHAPE0 geometry (256x128 tile, 64x64 waves) hardcoded. M=8192,N=1024,K=3072.
// Grid 256 = 32 mtiles x 8 ntiles, XCD-banded.
// ---------------------------------------------------------------------------
__global__ __launch_bounds__(512, 2) void gemm_y(
    const bf16* __restrict__ A, const bf16* __restrict__ Bt,
    const float* __restrict__ bsense, const float* __restrict__ sw,
    bf16* __restrict__ y)
{
  __shared__ __align__(16) bf16 As[3][256 * 32];
  __shared__ __align__(16) bf16 Bs[3][128 * 32];

  const int tid = threadIdx.x;
  const int lane = tid & 63;
  const int wave = tid >> 6;
  const int wr = wave >> 1, wc = wave & 1;

  // mtiles=32, ntiles=8, XCD-banded (per=4)
  const int bid = (int)blockIdx.x;
  const int xcd = bid & 7;
  const int slot = bid >> 3;            // 0..31
  const int by = xcd * 4 + (slot & 3);
  const int bx = slot >> 2;             // 0..7
  const int m0 = by * 256, n0 = bx * 128;

  const int r0 = tid >> 2, s0 = tid & 3;
  const int sc0 = (s0 ^ ((r0 >> 1) & 3)) * 8;
  const size_t a0 = (size_t)(m0 + r0) * 3072 + sc0;
  const size_t b0 = (size_t)(n0 + r0) * 3072 + sc0;
  const int ch1 = tid + 512;
  const int r1 = ch1 >> 2, s1 = ch1 & 3;
  const int sc1 = (s1 ^ ((r1 >> 1) & 3)) * 8;
  const size_t a1 = (size_t)(m0 + r1) * 3072 + sc1;

  floatx4 acc[4][4] = {};
  const int fm = lane & 15, fq = lane >> 4;
  const int gph = (fm >> 1) & 3;

  auto stage = [&](int buf, int t) {
    const int k0 = t * 32;
    async16(&A[a0 + k0], &As[buf][tid * 8]);
    async16(&A[a1 + k0], &As[buf][(tid + 512) * 8]);
    async16(&Bt[b0 + k0], &Bs[buf][tid * 8]);
  };

  stage(0, 0);
  stage(1, 1);
  asm volatile("s_waitcnt vmcnt(3)" ::: "memory");
  asm volatile("s_barrier" ::: "memory");

  int bufc = 0;
  for (int t = 0; t < 96; t++) {
    int bufn = bufc + 2; if (bufn >= 3) bufn -= 3;
    if (t + 2 < 96) stage(bufn, t + 2);
    short8 af[4], bfr[4];
#pragma unroll
    for (int i = 0; i < 4; i++) {
      int R = wr * 64 + i * 16 + fm;
      af[i] = *(const short8*)&As[bufc][R * 32 + ((fq ^ gph) << 3)];
    }
#pragma unroll
    for (int j = 0; j < 4; j++) {
      int R = wc * 64 + j * 16 + fm;
      bfr[j] = *(const short8*)&Bs[bufc][R * 32 + ((fq ^ gph) << 3)];
    }
#pragma unroll
    for (int i = 0; i < 4; i++)
#pragma unroll
      for (int j = 0; j < 4; j++)
        acc[i][j] = __builtin_amdgcn_mfma_f32_16x16x32_bf16(af[i], bfr[j], acc[i][j], 0, 0, 0);
    if (t + 2 < 96) asm volatile("s_waitcnt vmcnt(3)" ::: "memory");
    else            asm volatile("s_waitcnt vmcnt(0)" ::: "memory");
    asm volatile("s_barrier" ::: "memory");
    bufc++; if (bufc == 3) bufc = 0;
  }

  const int rm0 = (lane >> 4) * 4, cn = lane & 15;
#pragma unroll
  for (int j = 0; j < 4; j++) {
    int nn = n0 + wc * 64 + j * 16 + cn;
    float bb0 = bsense[nn], bb1 = bsense[1024 + nn], bb2 = bsense[2048 + nn];
#pragma unroll
    for (int i = 0; i < 4; i++) {
#pragma unroll
      for (int r = 0; r < 4; r++) {
        int mm = m0 + wr * 64 + i * 16 + rm0 + r;
        const float* sm = sw + (size_t)mm * 4;
        float v = acc[i][j][r] + sm[0] * bb0 + sm[1] * bb1 + sm[2] * bb2;
        y[(size_t)mm * 1024 + nn] = f2bf(v);
      }
    }
  }
}

// ---------------------------------------------------------------------------
// A'[t][s*1024+k] = bf16( sw_s[t] * x[t][k] )   (8192 x 3072)
// ---------------------------------------------------------------------------
__global__ __launch_bounds__(256) void k_prescale(const float* __restrict__ x,
                                                  const float* __restrict__ sw,
                                                  bf16* __restrict__ Ap) {
  long id = (long)blockIdx.x * 256 + threadIdx.x;
  if (id >= 1048576L) return;
  int t = (int)(id >> 7);
  int kc = (int)(id & 127) << 3;
  const float* xt = x + (size_t)t * 1024 + kc;
  float4 a = *(const float4*)xt;
  float4 b = *(const float4*)(xt + 4);
  const float s0 = sw[t * 4 + 0], s1 = sw[t * 4 + 1], s2 = sw[t * 4 + 2];
  float v[8] = {a.x, a.y, a.z, a.w, b.x, b.y, b.z, b.w};
  ushort8 o0, o1, o2;
#pragma unroll
  for (int e = 0; e < 8; e++) {
    o0[e] = f2bfu(s0 * v[e]);
    o1[e] = f2bfu(s1 * v[e]);
    o2[e] = f2bfu(s2 * v[e]);
  }
  bf16* row = Ap + (size_t)t * 3072 + kc;
  *(ushort8*)(row) = o0;
  *(ushort8*)(row + 1024) = o1;
  *(ushort8*)(row + 2048) = o2;
}

// ---------------------------------------------------------------------------
// x (fp32, 8192x1024) -> xhhl[t][3072] = [hi | hi | lo]
// ---------------------------------------------------------------------------
__global__ __launch_bounds__(256) void k_split_x3(const float* __restrict__ x,
                                                  bf16* __restrict__ xhhl) {
  long id = (long)blockIdx.x * 256 + threadIdx.x;
  if (id >= 8388608L) return;
  long t = id >> 10;
  int d = (int)(id & 1023);
  float v = x[id];
  bf16 h = f2bf(v);
  bf16 l = f2bf(v - bf2f(h));
  bf16* row = xhhl + t * 3072;
  row[d] = h;
  row[1024 + d] = h;
  row[2048 + d] = l;
}

// ---------------------------------------------------------------------------
// W_sense (fp32, 1024x3072) -> Wsn3[s][d][3072] = [hi | lo | hi]
// ---------------------------------------------------------------------------
__global__ __launch_bounds__(256) void k_split_ws3(const float* __restrict__ Ws,
                                                   bf16* __restrict__ Wsn3) {
  long id = (long)blockIdx.x * 256 + threadIdx.x;
  if (id >= 3145728L) return;
  int row10 = (int)(id >> 10);   // = d*3 + s
  int d = row10 / 3;
  int s = row10 - d * 3;
  int dp = (int)(id & 1023);
  float v = Ws[id];
  bf16 h = f2bf(v);
  bf16 l = f2bf(v - bf2f(h));
  bf16* row = Wsn3 + ((size_t)(s * 1024 + d)) * 3072;
  row[dp] = h;
  row[1024 + dp] = l;
  row[2048 + dp] = h;
}

// ---------------------------------------------------------------------------
// Transpose fp32 src[R][C] -> bf16 dh[C][R]
// ---------------------------------------------------------------------------
__global__ __launch_bounds__(256) void k_trans_hl(const float* __restrict__ src,
                                                  bf16* __restrict__ dh,
                                                  int R, int C) {
  __shared__ float tile[32][33];
  int c0 = blockIdx.x * 32, r0 = blockIdx.y * 32;
  int tx = threadIdx.x & 31, ty = threadIdx.x >> 5;
  for (int rr = ty; rr < 32; rr += 8)
    tile[rr][tx] = src[(size_t)(r0 + rr) * C + c0 + tx];
  __syncthreads();
  for (int rr = ty; rr < 32; rr += 8)
    dh[(size_t)(c0 + rr) * R + r0 + tx] = f2bf(tile[tx][rr]);
}

// ---------------------------------------------------------------------------
// Per-sense transpose: Bt2[d][s*1024+k] = W_sense[k][s*1024+d]  (bf16 hi)
// grid (32, 32, 3)
// ---------------------------------------------------------------------------
__global__ __launch_bounds__(256) void k_trans_sense(const float* __restrict__ Ws,
                                                     bf16* __restrict__ Bt2) {
  __shared__ float tile[32][33];
  int c0 = blockIdx.x * 32, r0 = blockIdx.y * 32, s = blockIdx.z;
  int tx = threadIdx.x & 31, ty = threadIdx.x >> 5;
  for (int rr = ty; rr < 32; rr += 8)
    tile[rr][tx] = Ws[(size_t)(r0 + rr) * 3072 + s * 1024 + c0 + tx];
  __syncthreads();
  for (int rr = ty; rr < 32; rr += 8)
    Bt2[(size_t)(c0 + rr) * 3072 + s * 1024 + r0 + tx] = f2bf(tile[tx][rr]);
}

// ---------------------------------------------------------------------------
// Pack head weights -> Whhl3[c][3072] = [hi | hi | lo]; bhead[37]; csig[1024]
// ---------------------------------------------------------------------------
__global__ __launch_bounds__(256) void k_pack(
    const float* __restrict__ W_charge, const float* __restrict__ W_shell,
    const float* __restrict__ W_class, const float* __restrict__ W_mass,
    const float* __restrict__ b_charge, const float* __restrict__ b_shell,
    const float* __restrict__ b_class, const float* __restrict__ b_mass,
    const float* __restrict__ compat_logits,
    bf16* __restrict__ Whhl3, float* __restrict__ bhead, float* __restrict__ csig)
{
  int c = blockIdx.x;
  int tid = threadIdx.x;
  for (int e = tid; e < 1024; e += 256) {
    float v;
    if (c == 0) v = W_charge[e];
    else if (c < 4) v = W_shell[e * 3 + (c - 1)];
    else if (c == 4) v = W_mass[e];
    else if (c < 37) v = W_class[e * 32 + (c - 5)];
    else v = 0.0f;
    bf16 h = f2bf(v);
    bf16 l = f2bf(v - bf2f(h));
    bf16* row = Whhl3 + (size_t)c * 3072;
    row[e] = h;
    row[1024 + e] = h;
    row[2048 + e] = l;
  }
  if (c == 0 && tid < 37) {
    float v;
    if (tid == 0) v = b_charge[0];
    else if (tid < 4) v = b_shell[tid - 1];
    else if (tid == 4) v = b_mass[0];
    else v = b_class[tid - 5];
    bhead[tid] = v;
  }
  if (c == 1) {
    for (int k = tid; k < 1024; k += 256) {
      int ii = k >> 5, jj = k & 31;
      float l = 0.5f * (compat_logits[ii * 32 + jj] + compat_logits[jj * 32 + ii]);
      csig[k] = 1.0f / (1.0f + expf(-l));
    }
  }
}

// ---------------------------------------------------------------------------
// bh[s][c] = b_sense_s . W_head_col_c  (exact fp32)
// ---------------------------------------------------------------------------
__global__ __launch_bounds__(256) void k_bh(
    const float* __restrict__ b_sense, const float* __restrict__ W_charge,
    const float* __restrict__ W_shell, const float* __restrict__ W_class,
    const float* __restrict__ W_mass, float* __restrict__ bh)
{
  const int c = blockIdx.x, s = blockIdx.y;
  const int tid = threadIdx.x;
  __shared__ float red[256];
  float p = 0.0f;
  for (int e = tid; e < 1024; e += 256) {
    float w;
    if (c == 0) w = W_charge[e];
    else if (c < 4) w = W_shell[e * 3 + (c - 1)];
    else if (c == 4) w = W_mass[e];
    else w = W_class[e * 32 + (c - 5)];
    p += b_sense[s * 1024 + e] * w;
  }
  red[tid] = p;
  __syncthreads();
  for (int st = 128; st > 0; st >>= 1) {
    if (tid < st) red[tid] += red[tid + st];
    __syncthreads();
  }
  if (tid == 0) bh[s * 128 + c] = red[0];
}

// ---------------------------------------------------------------------------
// Mt partial reduce: Mt[s][i] = sum_kc Mtp[s*8+kc][i]
// ---------------------------------------------------------------------------
__global__ __launch_bounds__(256) void k_reduce_mt(const float* __restrict__ Mtp,
                                                   float* __restrict__ Mt) {
  long o = (long)blockIdx.x * 256 + threadIdx.x;
  if (o >= 393216L) return;
  long s = o >> 17;
  long i = o & 131071;
  const float* p = Mtp + s * 8 * 131072 + i;
  float acc = 0.0f;
#pragma unroll
  for (int kc = 0; kc < 8; kc++) acc += p[(size_t)kc * 131072];
  Mt[o] = acc;
}

// ---------------------------------------------------------------------------
// Mt (fp32 [3][128][1024]) + W_sel -> Mthl[512][3072] = [hi | lo | hi]
// ---------------------------------------------------------------------------
__global__ __launch_bounds__(256) void k_split(const float* __restrict__ Mt,
                                               const float* __restrict__ W_sel,
                                               bf16* __restrict__ Mthl) {
  long id = (long)blockIdx.x * 256 + threadIdx.x;   // 512*3072
  if (id >= 1572864L) return;
  int n = (int)(id / 3072);
  int k = (int)(id - (long)n * 3072);
  int third = k >> 10;
  int j = k & 1023;
  float v;
  if (n < 384) {
    v = Mt[(size_t)n * 1024 + j];
  } else {
    int c2 = n - 384;
    v = (c2 < 3) ? W_sel[(size_t)j * 3 + c2] : 0.0f;
  }
  bf16 h = f2bf(v);
  Mthl[id] = (third == 1) ? f2bf(v - bf2f(h)) : h;
}

// ---------------------------------------------------------------------------
// xbar[b][d] = mean_n x[b][n][d]
// ---------------------------------------------------------------------------
__global__ __launch_bounds__(256) void k_xbar(const float* __restrict__ x, float* __restrict__ xbar) {
  const int d = blockIdx.x * 256 + threadIdx.x;
  const int b = blockIdx.y;
  const int n0 = blockIdx.z * 256;
  const float* xb = x + (size_t)b * 2048 * 1024 + (size_t)n0 * 1024 + d;
  float s = 0.0f;
  for (int n = 0; n < 256; n++) s += xb[(size_t)n * 1024];
  atomicAdd(&xbar[b * 1024 + d], s * (1.0f / 2048.0f));
}

// ---------------------------------------------------------------------------
// q[e][s] = sum_d W_ctx[e][d]*W_sel[1024+d][s]; q[1024][s] from b_ctx
// ---------------------------------------------------------------------------
__global__ __launch_bounds__(256) void k_q(const float* __restrict__ W_ctx,
                                           const float* __restrict__ b_ctx,
                                           const float* __restrict__ W_sel,
                                           float* __restrict__ q) {
  const int e = blockIdx.x;
  const int tid = threadIdx.x;
  const float* row = (e < 1024) ? (W_ctx + (size_t)e * 1024) : b_ctx;
  float p0 = 0.0f, p1 = 0.0f, p2 = 0.0f;
  for (int d = tid; d < 1024; d += 256) {
    float v = row[d];
    const float* ws = W_sel + (size_t)(1024 + d) * 3;
    p0 += v * ws[0]; p1 += v * ws[1]; p2 += v * ws[2];
  }
  __shared__ float red[3][256];
  red[0][tid] = p0; red[1][tid] = p1; red[2][tid] = p2;
  __syncthreads();
  for (int st = 128; st > 0; st >>= 1) {
    if (tid < st) {
      red[0][tid] += red[0][tid + st];
      red[1][tid] += red[1][tid + st];
      red[2][tid] += red[2][tid + st];
    }
    __syncthreads();
  }
  if (tid < 3) q[(size_t)e * 3 + tid] = red[tid][0];
}

// ---------------------------------------------------------------------------
__global__ __launch_bounds__(256) void k_ctxsel(const float* __restrict__ xbar,
                                                const float* __restrict__ q,
                                                float* __restrict__ ctx_sel) {
  const int b = blockIdx.x;
  const int tid = threadIdx.x;
  float p0 = 0.0f, p1 = 0.0f, p2 = 0.0f;
  for (int e = tid; e < 1024; e += 256) {
    float v = xbar[b * 1024 + e];
    p0 += v * q[e * 3 + 0]; p1 += v * q[e * 3 + 1]; p2 += v * q[e * 3 + 2];
  }
  __shared__ float red[3][256];
  red[0][tid] = p0; red[1][tid] = p1; red[2][tid] = p2;
  __syncthreads();
  for (int st = 128; st > 0; st >>= 1) {
    if (tid < st) {
      red[0][tid] += red[0][tid + st];
      red[1][tid] += red[1][tid + st];
      red[2][tid] += red[2][tid + st];
    }
    __syncthreads();
  }
  if (tid < 3) ctx_sel[b * 3 + tid] = red[tid][0] + q[1024 * 3 + tid];
}

// ---------------------------------------------------------------------------
// Per token: sense softmax weights -> sw[t][4]; head features -> feat[t][8]
// 4 tokens per 256-thread block (64-lane groups). H = 2 split-K planes.
// ---------------------------------------------------------------------------
__global__ __launch_bounds__(256) void k_heads(
    const float* __restrict__ H, const float* __restrict__ ctx_sel,
    const float* __restrict__ b_sel, const float* __restrict__ bh,
    const float* __restrict__ bhead,
    float* __restrict__ sw, float* __restrict__ feat)
{
  const int g = threadIdx.x >> 6;
  const int lane = threadIdx.x & 63;
  const int t = blockIdx.x * 4 + g;
  const int b = t >> 11;
  const float* Ht = H + (size_t)t * 512;
  const float* Ht2 = H + 4194304 + (size_t)t * 512;

  float s0 = Ht[384] + Ht2[384] + ctx_sel[b * 3 + 0] + b_sel[0];
  float s1 = Ht[385] + Ht2[385] + ctx_sel[b * 3 + 1] + b_sel[1];
  float s2 = Ht[386] + Ht2[386] + ctx_sel[b * 3 + 2] + b_sel[2];
  float mx = fmaxf(s0, fmaxf(s1, s2));
  float e0 = expf(s0 - mx), e1 = expf(s1 - mx), e2 = expf(s2 - mx);
  float inv = 1.0f / (e0 + e1 + e2);
  float w0 = e0 * inv, w1 = e1 * inv, w2 = e2 * inv;

  __shared__ float L[4][64];
  if (lane < 37) {
    float lg = bhead[lane];
    lg += w0 * (Ht[lane] + Ht2[lane] + bh[lane]);
    lg += w1 * (Ht[128 + lane] + Ht2[128 + lane] + bh[128 + lane]);
    lg += w2 * (Ht[256 + lane] + Ht2[256 + lane] + bh[256 + lane]);
    L[g][lane] = lg;
  }
  __syncthreads();
  if (lane == 0) {
    float charge = tanhf(L[g][0]);
    float h0 = L[g][1], h1 = L[g][2], h2 = L[g][3];
    float hm = fmaxf(h0, fmaxf(h1, h2));
    float x0 = expf(h0 - hm), x1 = expf(h1 - hm), x2 = expf(h2 - hm);
    float hinv = 1.0f / (x0 + x1 + x2);
    float mass = softplusf(L[g][4]) + 0.5f;
    int cls = 0;
    float best = L[g][5];
    for (int c = 1; c < 32; c++) {
      if (L[g][5 + c] > best) { best = L[g][5 + c]; cls = c; }
    }
    float* f = feat + (size_t)t * 8;
    f[0] = charge; f[1] = mass;
    f[2] = x0 * hinv; f[3] = x1 * hinv; f[4] = x2 * hinv;
    f[5] = (float)cls; f[6] = 0.0f; f[7] = 0.0f;
    float* sp_ = sw + (size_t)t * 4;
    sp_[0] = w0; sp_[1] = w1; sp_[2] = w2; sp_[3] = 0.0f;
  }
}

// ---------------------------------------------------------------------------
__global__ __launch_bounds__(256) void k_scores(
    const float* __restrict__ feat, const float* __restrict__ compat,
    const float* __restrict__ wchg, const float* __restrict__ wsh,
    const float* __restrict__ wdist, const float* __restrict__ wmass,
    const float* __restrict__ wval, const float* __restrict__ temp_p,
    bf16* __restrict__ P)
{
  const int i = blockIdx.x, b = blockIdx.y;
  const int tid = threadIdx.x;
  __shared__ float cs[1024];
  __shared__ float red[256];
  for (int k = tid; k < 1024; k += 256) cs[k] = compat[k];
  __syncthreads();

  const float a = softplusf(wchg[0]);
  const float bs = softplusf(wsh[0]);
  const float c = softplusf(wdist[0]);
  const float dm = softplusf(wmass[0]);
  const float ev = softplusf(wval[0]);
  const float itmp = 1.0f / softplusf(temp_p[0]);

  const float4* fi4 = (const float4*)(feat + ((size_t)b * 2048 + i) * 8);
  float4 fiA = fi4[0], fiB = fi4[1];
  const float ci = fiA.x, mi = fiA.y, si0 = fiA.z, si1 = fiA.w, si2 = fiB.x;
  int cli = (int)fiB.y; cli = cli < 0 ? 0 : (cli > 31 ? 31 : cli);

  float sc[8];
  float lmax = -3.0e38f;
#pragma unroll
  for (int jj = 0; jj < 8; jj++) {
    int j = tid + jj * 256;
    const float4* fj4 = (const float4*)(feat + ((size_t)b * 2048 + j) * 8);
    float4 fjA = fj4[0], fjB = fj4[1];
    int clj = (int)fjB.y; clj = clj < 0 ? 0 : (clj > 31 ? 31 : clj);
    float E = a * ci * fjA.x
            + bs * (fabsf(si0 - fjA.z) + fabsf(si1 - fjA.w) + fabsf(si2 - fjB.x))
            - c / (1.0f + 0.1f * fabsf((float)(i - j)))
            + dm * 0.1f * mi * fjA.y
            - ev;
    float s = (j <= i) ? (-E * itmp) * cs[cli * 32 + clj] : -3.0e38f;
    sc[jj] = s;
    lmax = fmaxf(lmax, s);
  }
  red[tid] = lmax;
  __syncthreads();
  for (int st = 128; st > 0; st >>= 1) {
    if (tid < st) red[tid] = fmaxf(red[tid], red[tid + st]);
    __syncthreads();
  }
  const float mrow = red[0];
  __syncthreads();

  float pv[8];
  float lsum = 0.0f;
#pragma unroll
  for (int jj = 0; jj < 8; jj++) {
    pv[jj] = (sc[jj] > -1.0e37f) ? expf(sc[jj] - mrow) : 0.0f;
    lsum += pv[jj];
  }
  red[tid] = lsum;
  __syncthreads();
  for (int st = 128; st > 0; st >>= 1) {
    if (tid < st) red[tid] += red[tid + st];
    __syncthreads();
  }
  const float inv = 1.0f / red[0];
  bf16* Pi = P + ((size_t)b * 2048 + i) * 2048;
#pragma unroll
  for (int jj = 0; jj < 8; jj++) Pi[tid + jj * 256] = f2bf(pv[jj] * inv);
}

// ---------------------------------------------------------------------------
extern "C" void kernel_launch(void* const* d_in, const int* in_sizes, int n_in,
                              void* d_out, int out_size, void* d_ws, size_t ws_size,
                              hipStream_t stream) {
  (void)in_sizes; (void)n_in; (void)out_size; (void)ws_size;
  const float* x        = (const float*)d_in[0];
  const float* W_sense  = (const float*)d_in[1];
  const float* b_sense  = (const float*)d_in[2];
  const float* W_ctx    = (const float*)d_in[3];
  const float* b_ctx    = (const float*)d_in[4];
  const float* W_sel    = (const float*)d_in[5];
  const float* b_sel    = (const float*)d_in[6];
  const float* W_charge = (const float*)d_in[7];
  const float* b_charge = (const float*)d_in[8];
  const float* W_shell  = (const float*)d_in[9];
  const float* b_shell  = (const float*)d_in[10];
  const float* W_class  = (const float*)d_in[11];
  const float* b_class  = (const float*)d_in[12];
  const float* W_mass   = (const float*)d_in[13];
  const float* b_mass   = (const float*)d_in[14];
  const float* compat_logits = (const float*)d_in[17];
  const float* w_charge = (const float*)d_in[18];
  const float* w_shell  = (const float*)d_in[19];
  const float* w_distance = (const float*)d_in[20];
  const float* w_mass   = (const float*)d_in[21];
  const float* w_valence = (const float*)d_in[22];
  const float* temperature = (const float*)d_in[23];
  const float* W_v      = (const float*)d_in[24];
  const float* b_v      = (const float*)d_in[25];
  const float* W_out    = (const float*)d_in[26];
  const float* b_out    = (const float*)d_in[27];

  char* w = (char*)d_ws;
  auto alloc = [&](size_t bytes) {
    char* p = w;
    w += (bytes + 255) & ~(size_t)255;
    return p;
  };
  bf16* xhhl  = (bf16*)alloc(8192ULL * 3072 * 2);
  char* R1    = alloc(48ULL * 1024 * 1024);
  bf16* Wsn3  = (bf16*)R1;
  float* Hh   = (float*)R1;
  float* Mtp  = (float*)(R1 + 20ULL * 1024 * 1024);      // [24][131072] fp32
  bf16* Mthl  = (bf16*)(R1 + 40ULL * 1024 * 1024);       // [512][3072] bf16
  float* Mt   = (float*)(R1 + 44ULL * 1024 * 1024);      // [3][128][1024] fp32
  bf16* y     = (bf16*)R1;                               // [8192][1024] bf16
  bf16* Wts2  = (bf16*)alloc(3072ULL * 1024 * 2);        // Bt2 [1024][3072]
  bf16* Wt_v  = (bf16*)alloc(1024ULL * 1024 * 2);
  bf16* Wt_out = (bf16*)alloc(1024ULL * 1024 * 2);
  bf16* Whhl3 = (bf16*)alloc(128ULL * 3072 * 2);
  float* bh   = (float*)alloc(3ULL * 128 * 4);
  float* bhead = (float*)alloc(256);
  float* csig = (float*)alloc(4096);
  float* xbar = (float*)alloc(4ULL * 1024 * 4);
  float* qbuf = (float*)alloc(1025ULL * 3 * 4);
  float* ctx_sel = (float*)alloc(256);
  float* feat = (float*)alloc(8192ULL * 8 * 4);
  float* sw   = (float*)alloc(8192ULL * 4 * 4);
  bf16* Aprime = xhhl;                // [8192][3072]
  bf16* Vt = xhhl + 8388608;          // 16 MB
  bf16* O  = xhhl + 16777216;         // 16 MB
  bf16* P  = (bf16*)d_out;            // 32 MiB; consumed before final GEMM

  // ---- input conversions ----
  k_split_x3<<<32768, 256, 0, stream>>>(x, xhhl);
  k_split_ws3<<<12288, 256, 0, stream>>>(W_sense, Wsn3);
  k_trans_sense<<<dim3(32, 32, 3), 256, 0, stream>>>(W_sense, Wts2);
  k_trans_hl<<<dim3(32, 32), 256, 0, stream>>>(W_v, Wt_v, 1024, 1024);
  k_trans_hl<<<dim3(32, 32), 256, 0, stream>>>(W_out, Wt_out, 1024, 1024);
  k_pack<<<128, 256, 0, stream>>>(W_charge, W_shell, W_class, W_mass,
                                  b_charge, b_shell, b_class, b_mass,
                                  compat_logits, Whhl3, bhead, csig);

  // ---- ctx path ----
  hipMemsetAsync(xbar, 0, 4096 * 4, stream);
  k_xbar<<<dim3(4, 4, 8), 256, 0, stream>>>(x, xbar);
  k_q<<<1025, 256, 0, stream>>>(W_ctx, b_ctx, W_sel, qbuf);
  k_ctxsel<<<4, 256, 0, stream>>>(xbar, qbuf, ctx_sel);

  // ---- Mt fold: SHAPE1 (M=128), 8-way K-split -> 192 blocks + reduce ----
  gemm_bt<1, 1, 0, 0, 0, 8><<<dim3(8, 1, 24), 512, 0, stream>>>(
      Whhl3, Wsn3, nullptr, Mtp, 128, 1024, 384, 3072, 3072, 1024,
      0, 3145728L, 131072L);
  k_reduce_mt<<<1536, 256, 0, stream>>>(Mtp, Mt);
  k_split<<<6144, 256, 0, stream>>>(Mt, W_sel, Mthl);

  // ---- H = x @ [Mt | Wsel]^T: SHAPE0, 2-way K-split -> 256 blocks ----
  gemm_bt<0, 1, 0, 0, 1, 2><<<dim3(128, 1, 2), 512, 0, stream>>>(
      xhhl, Mthl, nullptr, Hh, 8192, 512, 1536, 3072, 3072, 512,
      0, 0, 4194304L);

  // ---- bh (exact fp32) + per-token heads (sums the 2 H planes) ----
  k_bh<<<dim3(37, 3), 256, 0, stream>>>(b_sense, W_charge, W_shell, W_class, W_mass, bh);
  k_heads<<<2048, 256, 0, stream>>>(Hh, ctx_sel, b_sel, bh, bhead, sw, feat);

  // ---- A' = sw-prescaled x (overwrites xhhl; xhhl dead after H GEMM) ----
  k_prescale<<<4096, 256, 0, stream>>>(x, sw, Aprime);

  // ---- y = A' @ Bt2 + sw-weighted bias (SHAPE0 geometry, 256 blocks) ----
  gemm_y<<<256, 512, 0, stream>>>(Aprime, Wts2, b_sense, sw, y);

  // ---- V^T (batched): Vt[b][d][n]  SHAPE0, 256 blocks ----
  gemm_bt<0, 2, 0, 0, 1><<<256, 512, 0, stream>>>(
      y, Wt_v, b_v, Vt, 8192, 1024, 1024, 1024, 1024, 0, 0, 0, 0);

  // ---- P = causal softmax of pair scores (in d_out) ----
  k_scores<<<dim3(2048, 4), 256, 0, stream>>>(feat, csig, w_charge, w_shell,
                                              w_distance, w_mass, w_valence, temperature, P);

  // ---- O = P @ V: SHAPE1 causal (2 blocks/CU balances k-skew), per batch ----
  gemm_bt<1, 0, 1, 0, 0><<<dim3(8, 16, 4), 512, 0, stream>>>(
      P, Vt, nullptr, O, 2048, 1024, 2048, 2048, 2048, 1024,
      2048L * 2048, 1024L * 2048, 2048L * 1024);

  // ---- out = O @ W_out + b_out (fp32, SHAPE0, 256 blocks) ----
  gemm_bt<0, 1, 0, 0, 1><<<256, 512, 0, stream>>>(
      O, Wt_out, b_out, (float*)d_out, 8192, 1024, 1024, 1024, 1024, 1024, 0, 0, 0);
}

// Round 13
// 514.144 us; speedup vs baseline: 1.0823x; 1.0823x over previous
//
#include <hip/hip_runtime.h>
#include <hip/hip_bf16.h>
#include <cmath>

typedef __hip_bfloat16 bf16;
typedef __attribute__((ext_vector_type(4))) float floatx4;
typedef __attribute__((ext_vector_type(8))) short short8;
typedef __attribute__((ext_vector_type(8))) unsigned short ushort8;

__device__ __forceinline__ float bf2f(bf16 v) { return __bfloat162float(v); }
__device__ __forceinline__ bf16 f2bf(float v) { return __float2bfloat16(v); }
__device__ __forceinline__ float bfu2f(unsigned short u) { return __uint_as_float(((unsigned)u) << 16); }
__device__ __forceinline__ unsigned short f2bfu(float v) {
  bf16 h = __float2bfloat16(v);
  return __builtin_bit_cast(unsigned short, h);
}
__device__ __forceinline__ float softplusf(float x) {
  return x > 20.0f ? x : log1pf(expf(x));
}

__device__ __forceinline__ void async16(const void* g, void* l) {
  __builtin_amdgcn_global_load_lds(
      (const __attribute__((address_space(1))) unsigned int*)g,
      (__attribute__((address_space(3))) unsigned int*)l, 16, 0, 0);
}

// ---------------------------------------------------------------------------
// Generic bf16 GEMM: C[m][n] = sum_k A[m][k] * Bt[n][k]  (+ fp32 bias[n])
// [round-7 measured config: 515.7us total, gemm family MfmaUtil ~27%]
// 512 threads / 8 waves per block over a 128x128 tile (wave = 32x64 out:
// 2x4 frags of 16x16x32). Tri-buffered BK=32 with COUNTED vmcnt: at step t
// issue loads for tile t+2 (1 chunk/thread/matrix), compute tile t, then
// s_waitcnt vmcnt(2) (t+1's 2 loads per wave) + raw s_barrier. 48KB LDS ->
// 2 blocks/CU = 16 waves/CU (launch_bounds(512,4)).
// LDS swizzle (both-sides involution): physical 16B chunk c of row r holds
// logical chunk c ^ ((r>>1)&3); staged via pre-swizzled global source col.
// Read side: gph = (fm>>1)&3 == (R>>1)&3 because wr*32, wc*64, i*16 = 0 mod 4.
// MODE 0: bf16 out row-major (ldc).   MODE 1: fp32 out (ldc), ACCUM adds.
// MODE 2: bf16 out transposed-batched: out[((m>>11)*1024 + n)*2048 + (m&2047)]
// CAUSAL: k limited to (m_tile+1)*128; m-tiles issued heavy-first.
// SWZ: flat grid.x = mtiles*ntiles; XCD-banded decode (bid&7 -> m band).
// KSPLIT>1: z = zz*KSPLIT + kc; K is the CHUNK length, kstart = kc*K.
// All K chunks must be multiples of 32.
// ---------------------------------------------------------------------------
template<int MODE, int CAUSAL, int ACCUM, int SWZ, int KSPLIT = 1>
__global__ __launch_bounds__(512, 4) void gemm_bt(
    const bf16* __restrict__ A, const bf16* __restrict__ Bt,
    const float* __restrict__ bias, void* __restrict__ Cptr,
    int M, int N, int K, int lda, int ldb, int ldc,
    long aoffz, long boffz, long coffz)
{
  __shared__ __align__(16) bf16 As[3][128 * 32];
  __shared__ __align__(16) bf16 Bs[3][128 * 32];

  const int tid = threadIdx.x;
  const int lane = tid & 63;
  const int wave = tid >> 6;            // 0..7
  const int wr = wave >> 1, wc = wave & 1;
  const long z = blockIdx.z;
  int kstart = 0;
  long zz = z;
  if (KSPLIT > 1) {
    kstart = (int)(z % KSPLIT) * K;
    zz = z / KSPLIT;
  }
  A += zz * aoffz;
  Bt += zz * boffz;

  int bx, by;
  if (SWZ) {
    const int mtiles = M >> 7;
    const int per = mtiles >> 3;          // m-tiles per XCD band
    const int bid = (int)blockIdx.x;
    const int xcd = bid & 7;
    const int slot = bid >> 3;
    by = xcd * per + (slot % per);
    bx = slot / per;
  } else {
    bx = blockIdx.x;
    by = blockIdx.y;
    if (CAUSAL) by = (int)gridDim.y - 1 - by;   // heavy tiles first
  }
  const int m0 = by * 128, n0 = bx * 128;
  int kend = kstart + K;
  if (CAUSAL) {
    int klim = (by + 1) * 128;
    if (klim < kend) kend = klim;
  }

  // Staging: 512 chunks of 16B per 128x32 tile; 1 chunk/thread/matrix.
  // chunk tid -> row srow = tid>>2, slot sc = tid&3; src logical chunk
  // sc ^ ((srow>>1)&3).
  const int srow = tid >> 2, sc = tid & 3;
  const int scol = (sc ^ ((srow >> 1) & 3)) * 8;
  const size_t a0 = (size_t)(m0 + srow) * lda + scol;
  const size_t b0 = (size_t)(n0 + srow) * ldb + scol;

  floatx4 acc[2][4] = {};
  const int fm = lane & 15, fq = lane >> 4;
  const int gph = (fm >> 1) & 3;
  const int nt = (kend - kstart) >> 5;

  auto stage = [&](int buf, int t) {
    const int k0 = kstart + t * 32;
    async16(&A[a0 + k0], &As[buf][tid * 8]);
    async16(&Bt[b0 + k0], &Bs[buf][tid * 8]);
  };

  stage(0, 0);
  if (nt > 1) {
    stage(1, 1);
    asm volatile("s_waitcnt vmcnt(2)" ::: "memory");
  } else {
    asm volatile("s_waitcnt vmcnt(0)" ::: "memory");
  }
  asm volatile("s_barrier" ::: "memory");

  int bufc = 0;
  for (int t = 0; t < nt; t++) {
    int bufn = bufc + 2; if (bufn >= 3) bufn -= 3;
    if (t + 2 < nt) stage(bufn, t + 2);
    short8 af[2], bfr[4];
#pragma unroll
    for (int i = 0; i < 2; i++) {
      int R = wr * 32 + i * 16 + fm;
      af[i] = *(const short8*)&As[bufc][R * 32 + ((fq ^ gph) << 3)];
    }
#pragma unroll
    for (int j = 0; j < 4; j++) {
      int R = wc * 64 + j * 16 + fm;
      bfr[j] = *(const short8*)&Bs[bufc][R * 32 + ((fq ^ gph) << 3)];
    }
#pragma unroll
    for (int i = 0; i < 2; i++)
#pragma unroll
      for (int j = 0; j < 4; j++)
        acc[i][j] = __builtin_amdgcn_mfma_f32_16x16x32_bf16(af[i], bfr[j], acc[i][j], 0, 0, 0);
    if (t + 2 < nt) asm volatile("s_waitcnt vmcnt(2)" ::: "memory");
    else            asm volatile("s_waitcnt vmcnt(0)" ::: "memory");
    asm volatile("s_barrier" ::: "memory");
    bufc++; if (bufc == 3) bufc = 0;
  }

  const int rm0 = (lane >> 4) * 4, cn = lane & 15;
#pragma unroll
  for (int i = 0; i < 2; i++) {
#pragma unroll
    for (int j = 0; j < 4; j++) {
      int nn = n0 + wc * 64 + j * 16 + cn;
      float bv = bias ? bias[nn] : 0.0f;
#pragma unroll
      for (int r = 0; r < 4; r++) {
        int mm = m0 + wr * 32 + i * 16 + rm0 + r;
        float v = acc[i][j][r] + bv;
        if (MODE == 0) {
          ((bf16*)Cptr)[z * coffz + (long)mm * ldc + nn] = f2bf(v);
        } else if (MODE == 1) {
          long idx = z * coffz + (long)mm * ldc + nn;
          float* Cf = (float*)Cptr;
          if (ACCUM) v += Cf[idx];
          Cf[idx] = v;
        } else {
          long idx = ((long)((mm >> 11) * 1024 + nn)) * 2048 + (mm & 2047);
          ((bf16*)Cptr)[idx] = f2bf(v);
        }
      }
    }
  }
}

// ---------------------------------------------------------------------------
// Fused y GEMM: y[t][d] = sum_s sw_s[t] * (x[t] @ W_sense_s)[d] + sw-wtd bias
// A = xhhl hi third (bf16 x, lda=3072, cols [0,1024)); no A' materialization.
// K' = 3072 = 3 senses x 1024; step t covers sense s = t>>5, x-cols
// ((t*32) & 1023). A-frag lanes each hold ONE m-row -> sense scale is a
// per-lane scalar mul applied in-register after the ds_read (rounded to
// bf16, same rounding class as the previous prescale path).
// Same round-7 structure: 8 waves 32x64, tri-buffer BK=32, vmcnt(2), swizzle.
// Grid 512 = 64 mtiles x 8 ntiles, XCD-banded. Bt2[d][s*1024+k] per-sense.
// ---------------------------------------------------------------------------
__global__ __launch_bounds__(512, 4) void gemm_y(
    const bf16* __restrict__ A, const bf16* __restrict__ Bt,
    const float* __restrict__ bsense, const float* __restrict__ sw,
    bf16* __restrict__ y)
{
  __shared__ __align__(16) bf16 As[3][128 * 32];
  __shared__ __align__(16) bf16 Bs[3][128 * 32];

  const int tid = threadIdx.x;
  const int lane = tid & 63;
  const int wave = tid >> 6;
  const int wr = wave >> 1, wc = wave & 1;

  // mtiles=64, ntiles=8, XCD-banded
  const int bid = (int)blockIdx.x;
  const int xcd = bid & 7;
  const int slot = bid >> 3;
  const int by = xcd * 8 + (slot & 7);
  const int bx = slot >> 3;
  const int m0 = by * 128, n0 = bx * 128;

  const int srow = tid >> 2, sc = tid & 3;
  const int scol = (sc ^ ((srow >> 1) & 3)) * 8;
  const size_t a0 = (size_t)(m0 + srow) * 3072 + scol;   // x hi third
  const size_t b0 = (size_t)(n0 + srow) * 3072 + scol;

  floatx4 acc[2][4] = {};
  const int fm = lane & 15, fq = lane >> 4;
  const int gph = (fm >> 1) & 3;

  // per-lane sense scales for the 2 A-frag rows (row = wr*32 + i*16 + fm)
  float sv0[2], sv1[2], sv2[2];
#pragma unroll
  for (int i = 0; i < 2; i++) {
    const float* sm = sw + (size_t)(m0 + wr * 32 + i * 16 + fm) * 4;
    sv0[i] = sm[0]; sv1[i] = sm[1]; sv2[i] = sm[2];
  }

  auto stage = [&](int buf, int t) {
    const int k0a = (t * 32) & 1023;        // x repeats per sense
    const int k0b = t * 32;                  // B spans full 3072
    async16(&A[a0 + k0a], &As[buf][tid * 8]);
    async16(&Bt[b0 + k0b], &Bs[buf][tid * 8]);
  };

  stage(0, 0);
  stage(1, 1);
  asm volatile("s_waitcnt vmcnt(2)" ::: "memory");
  asm volatile("s_barrier" ::: "memory");

  int bufc = 0;
  for (int t = 0; t < 96; t++) {
    int bufn = bufc + 2; if (bufn >= 3) bufn -= 3;
    if (t + 2 < 96) stage(bufn, t + 2);
    const int s = t >> 5;                    // uniform per step
    short8 af[2], bfr[4];
#pragma unroll
    for (int i = 0; i < 2; i++) {
      int R = wr * 32 + i * 16 + fm;
      short8 raw = *(const short8*)&As[bufc][R * 32 + ((fq ^ gph) << 3)];
      float scl = (s == 0) ? sv0[i] : (s == 1) ? sv1[i] : sv2[i];
#pragma unroll
      for (int e = 0; e < 8; e++)
        af[i][e] = (short)f2bfu(scl * bfu2f((unsigned short)raw[e]));
    }
#pragma unroll
    for (int j = 0; j < 4; j++) {
      int R = wc * 64 + j * 16 + fm;
      bfr[j] = *(const short8*)&Bs[bufc][R * 32 + ((fq ^ gph) << 3)];
    }
#pragma unroll
    for (int i = 0; i < 2; i++)
#pragma unroll
      for (int j = 0; j < 4; j++)
        acc[i][j] = __builtin_amdgcn_mfma_f32_16x16x32_bf16(af[i], bfr[j], acc[i][j], 0, 0, 0);
    if (t + 2 < 96) asm volatile("s_waitcnt vmcnt(2)" ::: "memory");
    else            asm volatile("s_waitcnt vmcnt(0)" ::: "memory");
    asm volatile("s_barrier" ::: "memory");
    bufc++; if (bufc == 3) bufc = 0;
  }

  const int rm0 = (lane >> 4) * 4, cn = lane & 15;
#pragma unroll
  for (int j = 0; j < 4; j++) {
    int nn = n0 + wc * 64 + j * 16 + cn;
    float bb0 = bsense[nn], bb1 = bsense[1024 + nn], bb2 = bsense[2048 + nn];
#pragma unroll
    for (int i = 0; i < 2; i++) {
#pragma unroll
      for (int r = 0; r < 4; r++) {
        int mm = m0 + wr * 32 + i * 16 + rm0 + r;
        const float* sm = sw + (size_t)mm * 4;
        float v = acc[i][j][r] + sm[0] * bb0 + sm[1] * bb1 + sm[2] * bb2;
        y[(size_t)mm * 1024 + nn] = f2bf(v);
      }
    }
  }
}

// ---------------------------------------------------------------------------
// x (fp32, 8192x1024) -> xhhl[t][3072] = [hi | hi | lo]
// ---------------------------------------------------------------------------
__global__ __launch_bounds__(256) void k_split_x3(const float* __restrict__ x,
                                                  bf16* __restrict__ xhhl) {
  long id = (long)blockIdx.x * 256 + threadIdx.x;
  if (id >= 8388608L) return;
  long t = id >> 10;
  int d = (int)(id & 1023);
  float v = x[id];
  bf16 h = f2bf(v);
  bf16 l = f2bf(v - bf2f(h));
  bf16* row = xhhl + t * 3072;
  row[d] = h;
  row[1024 + d] = h;
  row[2048 + d] = l;
}

// ---------------------------------------------------------------------------
// W_sense (fp32, 1024x3072) -> Wsn3[s][d][3072] = [hi | lo | hi]
// ---------------------------------------------------------------------------
__global__ __launch_bounds__(256) void k_split_ws3(const float* __restrict__ Ws,
                                                   bf16* __restrict__ Wsn3) {
  long id = (long)blockIdx.x * 256 + threadIdx.x;
  if (id >= 3145728L) return;
  int row10 = (int)(id >> 10);   // = d*3 + s
  int d = row10 / 3;
  int s = row10 - d * 3;
  int dp = (int)(id & 1023);
  float v = Ws[id];
  bf16 h = f2bf(v);
  bf16 l = f2bf(v - bf2f(h));
  bf16* row = Wsn3 + ((size_t)(s * 1024 + d)) * 3072;
  row[dp] = h;
  row[1024 + dp] = l;
  row[2048 + dp] = h;
}

// ---------------------------------------------------------------------------
// Transpose fp32 src[R][C] -> bf16 dh[C][R]
// ---------------------------------------------------------------------------
__global__ __launch_bounds__(256) void k_trans_hl(const float* __restrict__ src,
                                                  bf16* __restrict__ dh,
                                                  int R, int C) {
  __shared__ float tile[32][33];
  int c0 = blockIdx.x * 32, r0 = blockIdx.y * 32;
  int tx = threadIdx.x & 31, ty = threadIdx.x >> 5;
  for (int rr = ty; rr < 32; rr += 8)
    tile[rr][tx] = src[(size_t)(r0 + rr) * C + c0 + tx];
  __syncthreads();
  for (int rr = ty; rr < 32; rr += 8)
    dh[(size_t)(c0 + rr) * R + r0 + tx] = f2bf(tile[tx][rr]);
}

// ---------------------------------------------------------------------------
// Per-sense transpose: Bt2[d][s*1024+k] = W_sense[k][s*1024+d]  (bf16 hi)
// grid (32, 32, 3)
// ---------------------------------------------------------------------------
__global__ __launch_bounds__(256) void k_trans_sense(const float* __restrict__ Ws,
                                                     bf16* __restrict__ Bt2) {
  __shared__ float tile[32][33];
  int c0 = blockIdx.x * 32, r0 = blockIdx.y * 32, s = blockIdx.z;
  int tx = threadIdx.x & 31, ty = threadIdx.x >> 5;
  for (int rr = ty; rr < 32; rr += 8)
    tile[rr][tx] = Ws[(size_t)(r0 + rr) * 3072 + s * 1024 + c0 + tx];
  __syncthreads();
  for (int rr = ty; rr < 32; rr += 8)
    Bt2[(size_t)(c0 + rr) * 3072 + s * 1024 + r0 + tx] = f2bf(tile[tx][rr]);
}

// ---------------------------------------------------------------------------
// Pack head weights -> Whhl3[c][3072] = [hi | hi | lo]; bhead[37]; csig[1024]
// ---------------------------------------------------------------------------
__global__ __launch_bounds__(256) void k_pack(
    const float* __restrict__ W_charge, const float* __restrict__ W_shell,
    const float* __restrict__ W_class, const float* __restrict__ W_mass,
    const float* __restrict__ b_charge, const float* __restrict__ b_shell,
    const float* __restrict__ b_class, const float* __restrict__ b_mass,
    const float* __restrict__ compat_logits,
    bf16* __restrict__ Whhl3, float* __restrict__ bhead, float* __restrict__ csig)
{
  int c = blockIdx.x;
  int tid = threadIdx.x;
  for (int e = tid; e < 1024; e += 256) {
    float v;
    if (c == 0) v = W_charge[e];
    else if (c < 4) v = W_shell[e * 3 + (c - 1)];
    else if (c == 4) v = W_mass[e];
    else if (c < 37) v = W_class[e * 32 + (c - 5)];
    else v = 0.0f;
    bf16 h = f2bf(v);
    bf16 l = f2bf(v - bf2f(h));
    bf16* row = Whhl3 + (size_t)c * 3072;
    row[e] = h;
    row[1024 + e] = h;
    row[2048 + e] = l;
  }
  if (c == 0 && tid < 37) {
    float v;
    if (tid == 0) v = b_charge[0];
    else if (tid < 4) v = b_shell[tid - 1];
    else if (tid == 4) v = b_mass[0];
    else v = b_class[tid - 5];
    bhead[tid] = v;
  }
  if (c == 1) {
    for (int k = tid; k < 1024; k += 256) {
      int ii = k >> 5, jj = k & 31;
      float l = 0.5f * (compat_logits[ii * 32 + jj] + compat_logits[jj * 32 + ii]);
      csig[k] = 1.0f / (1.0f + expf(-l));
    }
  }
}

// ---------------------------------------------------------------------------
// bh[s][c] = b_sense_s . W_head_col_c  (exact fp32)
// ---------------------------------------------------------------------------
__global__ __launch_bounds__(256) void k_bh(
    const float* __restrict__ b_sense, const float* __restrict__ W_charge,
    const float* __restrict__ W_shell, const float* __restrict__ W_class,
    const float* __restrict__ W_mass, float* __restrict__ bh)
{
  const int c = blockIdx.x, s = blockIdx.y;
  const int tid = threadIdx.x;
  __shared__ float red[256];
  float p = 0.0f;
  for (int e = tid; e < 1024; e += 256) {
    float w;
    if (c == 0) w = W_charge[e];
    else if (c < 4) w = W_shell[e * 3 + (c - 1)];
    else if (c == 4) w = W_mass[e];
    else w = W_class[e * 32 + (c - 5)];
    p += b_sense[s * 1024 + e] * w;
  }
  red[tid] = p;
  __syncthreads();
  for (int st = 128; st > 0; st >>= 1) {
    if (tid < st) red[tid] += red[tid + st];
    __syncthreads();
  }
  if (tid == 0) bh[s * 128 + c] = red[0];
}

// ---------------------------------------------------------------------------
// Mt partial reduce: Mt[s][i] = sum_kc Mtp[s*8+kc][i]
// ---------------------------------------------------------------------------
__global__ __launch_bounds__(256) void k_reduce_mt(const float* __restrict__ Mtp,
                                                   float* __restrict__ Mt) {
  long o = (long)blockIdx.x * 256 + threadIdx.x;
  if (o >= 393216L) return;
  long s = o >> 17;
  long i = o & 131071;
  const float* p = Mtp + s * 8 * 131072 + i;
  float acc = 0.0f;
#pragma unroll
  for (int kc = 0; kc < 8; kc++) acc += p[(size_t)kc * 131072];
  Mt[o] = acc;
}

// ---------------------------------------------------------------------------
// Mt (fp32 [3][128][1024]) + W_sel -> Mthl[512][3072] = [hi | lo | hi]
// ---------------------------------------------------------------------------
__global__ __launch_bounds__(256) void k_split(const float* __restrict__ Mt,
                                               const float* __restrict__ W_sel,
                                               bf16* __restrict__ Mthl) {
  long id = (long)blockIdx.x * 256 + threadIdx.x;   // 512*3072
  if (id >= 1572864L) return;
  int n = (int)(id / 3072);
  int k = (int)(id - (long)n * 3072);
  int third = k >> 10;
  int j = k & 1023;
  float v;
  if (n < 384) {
    v = Mt[(size_t)n * 1024 + j];
  } else {
    int c2 = n - 384;
    v = (c2 < 3) ? W_sel[(size_t)j * 3 + c2] : 0.0f;
  }
  bf16 h = f2bf(v);
  Mthl[id] = (third == 1) ? f2bf(v - bf2f(h)) : h;
}

// ---------------------------------------------------------------------------
// xbar[b][d] = mean_n x[b][n][d]
// ---------------------------------------------------------------------------
__global__ __launch_bounds__(256) void k_xbar(const float* __restrict__ x, float* __restrict__ xbar) {
  const int d = blockIdx.x * 256 + threadIdx.x;
  const int b = blockIdx.y;
  const int n0 = blockIdx.z * 256;
  const float* xb = x + (size_t)b * 2048 * 1024 + (size_t)n0 * 1024 + d;
  float s = 0.0f;
  for (int n = 0; n < 256; n++) s += xb[(size_t)n * 1024];
  atomicAdd(&xbar[b * 1024 + d], s * (1.0f / 2048.0f));
}

// ---------------------------------------------------------------------------
// q[e][s] = sum_d W_ctx[e][d]*W_sel[1024+d][s]; q[1024][s] from b_ctx
// ---------------------------------------------------------------------------
__global__ __launch_bounds__(256) void k_q(const float* __restrict__ W_ctx,
                                           const float* __restrict__ b_ctx,
                                           const float* __restrict__ W_sel,
                                           float* __restrict__ q) {
  const int e = blockIdx.x;
  const int tid = threadIdx.x;
  const float* row = (e < 1024) ? (W_ctx + (size_t)e * 1024) : b_ctx;
  float p0 = 0.0f, p1 = 0.0f, p2 = 0.0f;
  for (int d = tid; d < 1024; d += 256) {
    float v = row[d];
    const float* ws = W_sel + (size_t)(1024 + d) * 3;
    p0 += v * ws[0]; p1 += v * ws[1]; p2 += v * ws[2];
  }
  __shared__ float red[3][256];
  red[0][tid] = p0; red[1][tid] = p1; red[2][tid] = p2;
  __syncthreads();
  for (int st = 128; st > 0; st >>= 1) {
    if (tid < st) {
      red[0][tid] += red[0][tid + st];
      red[1][tid] += red[1][tid + st];
      red[2][tid] += red[2][tid + st];
    }
    __syncthreads();
  }
  if (tid < 3) q[(size_t)e * 3 + tid] = red[tid][0];
}

// ---------------------------------------------------------------------------
__global__ __launch_bounds__(256) void k_ctxsel(const float* __restrict__ xbar,
                                                const float* __restrict__ q,
                                                float* __restrict__ ctx_sel) {
  const int b = blockIdx.x;
  const int tid = threadIdx.x;
  float p0 = 0.0f, p1 = 0.0f, p2 = 0.0f;
  for (int e = tid; e < 1024; e += 256) {
    float v = xbar[b * 1024 + e];
    p0 += v * q[e * 3 + 0]; p1 += v * q[e * 3 + 1]; p2 += v * q[e * 3 + 2];
  }
  __shared__ float red[3][256];
  red[0][tid] = p0; red[1][tid] = p1; red[2][tid] = p2;
  __syncthreads();
  for (int st = 128; st > 0; st >>= 1) {
    if (tid < st) {
      red[0][tid] += red[0][tid + st];
      red[1][tid] += red[1][tid + st];
      red[2][tid] += red[2][tid + st];
    }
    __syncthreads();
  }
  if (tid < 3) ctx_sel[b * 3 + tid] = red[tid][0] + q[1024 * 3 + tid];
}

// ---------------------------------------------------------------------------
// Per token: sense softmax weights -> sw[t][4]; head features -> feat[t][8]
// 4 tokens per 256-thread block (64-lane groups). H = 2 split-K planes.
// ---------------------------------------------------------------------------
__global__ __launch_bounds__(256) void k_heads(
    const float* __restrict__ H, const float* __restrict__ ctx_sel,
    const float* __restrict__ b_sel, const float* __restrict__ bh,
    const float* __restrict__ bhead,
    float* __restrict__ sw, float* __restrict__ feat)
{
  const int g = threadIdx.x >> 6;
  const int lane = threadIdx.x & 63;
  const int t = blockIdx.x * 4 + g;
  const int b = t >> 11;
  const float* Ht = H + (size_t)t * 512;
  const float* Ht2 = H + 4194304 + (size_t)t * 512;

  float s0 = Ht[384] + Ht2[384] + ctx_sel[b * 3 + 0] + b_sel[0];
  float s1 = Ht[385] + Ht2[385] + ctx_sel[b * 3 + 1] + b_sel[1];
  float s2 = Ht[386] + Ht2[386] + ctx_sel[b * 3 + 2] + b_sel[2];
  float mx = fmaxf(s0, fmaxf(s1, s2));
  float e0 = expf(s0 - mx), e1 = expf(s1 - mx), e2 = expf(s2 - mx);
  float inv = 1.0f / (e0 + e1 + e2);
  float w0 = e0 * inv, w1 = e1 * inv, w2 = e2 * inv;

  __shared__ float L[4][64];
  if (lane < 37) {
    float lg = bhead[lane];
    lg += w0 * (Ht[lane] + Ht2[lane] + bh[lane]);
    lg += w1 * (Ht[128 + lane] + Ht2[128 + lane] + bh[128 + lane]);
    lg += w2 * (Ht[256 + lane] + Ht2[256 + lane] + bh[256 + lane]);
    L[g][lane] = lg;
  }
  __syncthreads();
  if (lane == 0) {
    float charge = tanhf(L[g][0]);
    float h0 = L[g][1], h1 = L[g][2], h2 = L[g][3];
    float hm = fmaxf(h0, fmaxf(h1, h2));
    float x0 = expf(h0 - hm), x1 = expf(h1 - hm), x2 = expf(h2 - hm);
    float hinv = 1.0f / (x0 + x1 + x2);
    float mass = softplusf(L[g][4]) + 0.5f;
    int cls = 0;
    float best = L[g][5];
    for (int c = 1; c < 32; c++) {
      if (L[g][5 + c] > best) { best = L[g][5 + c]; cls = c; }
    }
    float* f = feat + (size_t)t * 8;
    f[0] = charge; f[1] = mass;
    f[2] = x0 * hinv; f[3] = x1 * hinv; f[4] = x2 * hinv;
    f[5] = (float)cls; f[6] = 0.0f; f[7] = 0.0f;
    float* sp_ = sw + (size_t)t * 4;
    sp_[0] = w0; sp_[1] = w1; sp_[2] = w2; sp_[3] = 0.0f;
  }
}

// ---------------------------------------------------------------------------
__global__ __launch_bounds__(256) void k_scores(
    const float* __restrict__ feat, const float* __restrict__ compat,
    const float* __restrict__ wchg, const float* __restrict__ wsh,
    const float* __restrict__ wdist, const float* __restrict__ wmass,
    const float* __restrict__ wval, const float* __restrict__ temp_p,
    bf16* __restrict__ P)
{
  const int i = blockIdx.x, b = blockIdx.y;
  const int tid = threadIdx.x;
  __shared__ float cs[1024];
  __shared__ float red[256];
  for (int k = tid; k < 1024; k += 256) cs[k] = compat[k];
  __syncthreads();

  const float a = softplusf(wchg[0]);
  const float bs = softplusf(wsh[0]);
  const float c = softplusf(wdist[0]);
  const float dm = softplusf(wmass[0]);
  const float ev = softplusf(wval[0]);
  const float itmp = 1.0f / softplusf(temp_p[0]);

  const float4* fi4 = (const float4*)(feat + ((size_t)b * 2048 + i) * 8);
  float4 fiA = fi4[0], fiB = fi4[1];
  const float ci = fiA.x, mi = fiA.y, si0 = fiA.z, si1 = fiA.w, si2 = fiB.x;
  int cli = (int)fiB.y; cli = cli < 0 ? 0 : (cli > 31 ? 31 : cli);

  float sc[8];
  float lmax = -3.0e38f;
#pragma unroll
  for (int jj = 0; jj < 8; jj++) {
    int j = tid + jj * 256;
    const float4* fj4 = (const float4*)(feat + ((size_t)b * 2048 + j) * 8);
    float4 fjA = fj4[0], fjB = fj4[1];
    int clj = (int)fjB.y; clj = clj < 0 ? 0 : (clj > 31 ? 31 : clj);
    float E = a * ci * fjA.x
            + bs * (fabsf(si0 - fjA.z) + fabsf(si1 - fjA.w) + fabsf(si2 - fjB.x))
            - c / (1.0f + 0.1f * fabsf((float)(i - j)))
            + dm * 0.1f * mi * fjA.y
            - ev;
    float s = (j <= i) ? (-E * itmp) * cs[cli * 32 + clj] : -3.0e38f;
    sc[jj] = s;
    lmax = fmaxf(lmax, s);
  }
  red[tid] = lmax;
  __syncthreads();
  for (int st = 128; st > 0; st >>= 1) {
    if (tid < st) red[tid] = fmaxf(red[tid], red[tid + st]);
    __syncthreads();
  }
  const float mrow = red[0];
  __syncthreads();

  float pv[8];
  float lsum = 0.0f;
#pragma unroll
  for (int jj = 0; jj < 8; jj++) {
    pv[jj] = (sc[jj] > -1.0e37f) ? expf(sc[jj] - mrow) : 0.0f;
    lsum += pv[jj];
  }
  red[tid] = lsum;
  __syncthreads();
  for (int st = 128; st > 0; st >>= 1) {
    if (tid < st) red[tid] += red[tid + st];
    __syncthreads();
  }
  const float inv = 1.0f / red[0];
  bf16* Pi = P + ((size_t)b * 2048 + i) * 2048;
#pragma unroll
  for (int jj = 0; jj < 8; jj++) Pi[tid + jj * 256] = f2bf(pv[jj] * inv);
}

// ---------------------------------------------------------------------------
extern "C" void kernel_launch(void* const* d_in, const int* in_sizes, int n_in,
                              void* d_out, int out_size, void* d_ws, size_t ws_size,
                              hipStream_t stream) {
  (void)in_sizes; (void)n_in; (void)out_size; (void)ws_size;
  const float* x        = (const float*)d_in[0];
  const float* W_sense  = (const float*)d_in[1];
  const float* b_sense  = (const float*)d_in[2];
  const float* W_ctx    = (const float*)d_in[3];
  const float* b_ctx    = (const float*)d_in[4];
  const float* W_sel    = (const float*)d_in[5];
  const float* b_sel    = (const float*)d_in[6];
  const float* W_charge = (const float*)d_in[7];
  const float* b_charge = (const float*)d_in[8];
  const float* W_shell  = (const float*)d_in[9];
  const float* b_shell  = (const float*)d_in[10];
  const float* W_class  = (const float*)d_in[11];
  const float* b_class  = (const float*)d_in[12];
  const float* W_mass   = (const float*)d_in[13];
  const float* b_mass   = (const float*)d_in[14];
  const float* compat_logits = (const float*)d_in[17];
  const float* w_charge = (const float*)d_in[18];
  const float* w_shell  = (const float*)d_in[19];
  const float* w_distance = (const float*)d_in[20];
  const float* w_mass   = (const float*)d_in[21];
  const float* w_valence = (const float*)d_in[22];
  const float* temperature = (const float*)d_in[23];
  const float* W_v      = (const float*)d_in[24];
  const float* b_v      = (const float*)d_in[25];
  const float* W_out    = (const float*)d_in[26];
  const float* b_out    = (const float*)d_in[27];

  char* w = (char*)d_ws;
  auto alloc = [&](size_t bytes) {
    char* p = w;
    w += (bytes + 255) & ~(size_t)255;
    return p;
  };
  bf16* xhhl  = (bf16*)alloc(8192ULL * 3072 * 2);
  char* R1    = alloc(48ULL * 1024 * 1024);
  bf16* Wsn3  = (bf16*)R1;
  float* Hh   = (float*)R1;
  float* Mtp  = (float*)(R1 + 20ULL * 1024 * 1024);      // [24][131072] fp32
  bf16* Mthl  = (bf16*)(R1 + 40ULL * 1024 * 1024);       // [512][3072] bf16
  float* Mt   = (float*)(R1 + 44ULL * 1024 * 1024);      // [3][128][1024] fp32
  bf16* y     = (bf16*)R1;                               // [8192][1024] bf16
  bf16* Wts2  = (bf16*)alloc(3072ULL * 1024 * 2);        // Bt2 [1024][3072]
  bf16* Wt_v  = (bf16*)alloc(1024ULL * 1024 * 2);
  bf16* Wt_out = (bf16*)alloc(1024ULL * 1024 * 2);
  bf16* Whhl3 = (bf16*)alloc(128ULL * 3072 * 2);
  float* bh   = (float*)alloc(3ULL * 128 * 4);
  float* bhead = (float*)alloc(256);
  float* csig = (float*)alloc(4096);
  float* xbar = (float*)alloc(4ULL * 1024 * 4);
  float* qbuf = (float*)alloc(1025ULL * 3 * 4);
  float* ctx_sel = (float*)alloc(256);
  float* feat = (float*)alloc(8192ULL * 8 * 4);
  float* sw   = (float*)alloc(8192ULL * 4 * 4);
  // aliases inside xhhl (48 MB flat); Vt/O written only after gemm_y is done
  bf16* Vt = xhhl + 8388608;          // 16 MB
  bf16* O  = xhhl + 16777216;         // 16 MB
  bf16* P  = (bf16*)d_out;            // 32 MiB; consumed before final GEMM

  // ---- input conversions ----
  k_split_x3<<<32768, 256, 0, stream>>>(x, xhhl);
  k_split_ws3<<<12288, 256, 0, stream>>>(W_sense, Wsn3);
  k_trans_sense<<<dim3(32, 32, 3), 256, 0, stream>>>(W_sense, Wts2);
  k_trans_hl<<<dim3(32, 32), 256, 0, stream>>>(W_v, Wt_v, 1024, 1024);
  k_trans_hl<<<dim3(32, 32), 256, 0, stream>>>(W_out, Wt_out, 1024, 1024);
  k_pack<<<128, 256, 0, stream>>>(W_charge, W_shell, W_class, W_mass,
                                  b_charge, b_shell, b_class, b_mass,
                                  compat_logits, Whhl3, bhead, csig);

  // ---- ctx path ----
  hipMemsetAsync(xbar, 0, 4096 * 4, stream);
  k_xbar<<<dim3(4, 4, 8), 256, 0, stream>>>(x, xbar);
  k_q<<<1025, 256, 0, stream>>>(W_ctx, b_ctx, W_sel, qbuf);
  k_ctxsel<<<4, 256, 0, stream>>>(xbar, qbuf, ctx_sel);

  // ---- Mt fold: 8-way K-split (chunk=384) -> 192 blocks, then reduce ----
  gemm_bt<1, 0, 0, 0, 8><<<dim3(8, 1, 24), 512, 0, stream>>>(
      Whhl3, Wsn3, nullptr, Mtp, 128, 1024, 384, 3072, 3072, 1024,
      0, 3145728L, 131072L);
  k_reduce_mt<<<1536, 256, 0, stream>>>(Mtp, Mt);
  k_split<<<6144, 256, 0, stream>>>(Mt, W_sel, Mthl);

  // ---- H = x @ [Mt | Wsel]^T, 2-way K-split (chunk=1536) -> 512 blocks ----
  gemm_bt<1, 0, 0, 1, 2><<<dim3(256, 1, 2), 512, 0, stream>>>(
      xhhl, Mthl, nullptr, Hh, 8192, 512, 1536, 3072, 3072, 512,
      0, 0, 4194304L);

  // ---- bh (exact fp32) + per-token heads (sums the 2 H planes) ----
  k_bh<<<dim3(37, 3), 256, 0, stream>>>(b_sense, W_charge, W_shell, W_class, W_mass, bh);
  k_heads<<<2048, 256, 0, stream>>>(Hh, ctx_sel, b_sel, bh, bhead, sw, feat);

  // ---- y = sum_s sw_s*(x @ W_sense_s) + sw-wtd bias (fused, no A') ----
  gemm_y<<<512, 512, 0, stream>>>(xhhl, Wts2, b_sense, sw, y);

  // ---- V^T (batched): Vt[b][d][n] ----
  gemm_bt<2, 0, 0, 1><<<512, 512, 0, stream>>>(
      y, Wt_v, b_v, Vt, 8192, 1024, 1024, 1024, 1024, 0, 0, 0, 0);

  // ---- P = causal softmax of pair scores (in d_out) ----
  k_scores<<<dim3(2048, 4), 256, 0, stream>>>(feat, csig, w_charge, w_shell,
                                              w_distance, w_mass, w_valence, temperature, P);

  // ---- O = P @ V (causal k-limit, heavy-first), per batch ----
  gemm_bt<0, 1, 0, 0><<<dim3(8, 16, 4), 512, 0, stream>>>(
      P, Vt, nullptr, O, 2048, 1024, 2048, 2048, 2048, 1024,
      2048L * 2048, 1024L * 2048, 2048L * 1024);

  // ---- out = O @ W_out + b_out (fp32, overwrites P) ----
  gemm_bt<1, 0, 0, 1><<<512, 512, 0, stream>>>(
      O, Wt_out, b_out, (float*)d_out, 8192, 1024, 1024, 1024, 1024, 1024, 0, 0, 0);
}

// Round 14
// 503.062 us; speedup vs baseline: 1.1061x; 1.0220x over previous
//
#include <hip/hip_runtime.h>
#include <hip/hip_bf16.h>
#include <cmath>

typedef __hip_bfloat16 bf16;
typedef __attribute__((ext_vector_type(4))) float floatx4;
typedef __attribute__((ext_vector_type(8))) short short8;
typedef __attribute__((ext_vector_type(8))) unsigned short ushort8;

__device__ __forceinline__ float bf2f(bf16 v) { return __bfloat162float(v); }
__device__ __forceinline__ bf16 f2bf(float v) { return __float2bfloat16(v); }
__device__ __forceinline__ float bfu2f(unsigned short u) { return __uint_as_float(((unsigned)u) << 16); }
__device__ __forceinline__ unsigned short f2bfu(float v) {
  bf16 h = __float2bfloat16(v);
  return __builtin_bit_cast(unsigned short, h);
}
__device__ __forceinline__ float softplusf(float x) {
  return x > 20.0f ? x : log1pf(expf(x));
}

__device__ __forceinline__ void async16(const void* g, void* l) {
  __builtin_amdgcn_global_load_lds(
      (const __attribute__((address_space(1))) unsigned int*)g,
      (__attribute__((address_space(3))) unsigned int*)l, 16, 0, 0);
}

// ---------------------------------------------------------------------------
// Generic bf16 GEMM: C[m][n] = sum_k A[m][k] * Bt[n][k]  (+ fp32 bias[n])
// [round-7 measured config: gemm family MfmaUtil ~27%]
// 512 threads / 8 waves per block over a 128x128 tile (wave = 32x64 out:
// 2x4 frags of 16x16x32). Tri-buffered BK=32 with COUNTED vmcnt: at step t
// issue loads for tile t+2 (1 chunk/thread/matrix), compute tile t, then
// s_waitcnt vmcnt(2) (t+1's 2 loads per wave) + raw s_barrier. 48KB LDS ->
// 2 blocks/CU = 16 waves/CU (launch_bounds(512,4)).
// LDS swizzle (both-sides involution): physical 16B chunk c of row r holds
// logical chunk c ^ ((r>>1)&3); staged via pre-swizzled global source col.
// Read side: gph = (fm>>1)&3 == (R>>1)&3 because wr*32, wc*64, i*16 = 0 mod 4.
// MODE 0: bf16 out row-major (ldc).   MODE 1: fp32 out (ldc), ACCUM adds.
// MODE 2: bf16 out transposed-batched: out[((m>>11)*1024 + n)*2048 + (m&2047)]
// CAUSAL: k limited to (m_tile+1)*128; m-tiles issued heavy-first.
// SWZ: flat grid.x = mtiles*ntiles; XCD-banded decode (bid&7 -> m band).
// KSPLIT>1: z = zz*KSPLIT + kc; K is the CHUNK length, kstart = kc*K.
// All K chunks must be multiples of 32.
// ---------------------------------------------------------------------------
template<int MODE, int CAUSAL, int ACCUM, int SWZ, int KSPLIT = 1>
__global__ __launch_bounds__(512, 4) void gemm_bt(
    const bf16* __restrict__ A, const bf16* __restrict__ Bt,
    const float* __restrict__ bias, void* __restrict__ Cptr,
    int M, int N, int K, int lda, int ldb, int ldc,
    long aoffz, long boffz, long coffz)
{
  __shared__ __align__(16) bf16 As[3][128 * 32];
  __shared__ __align__(16) bf16 Bs[3][128 * 32];

  const int tid = threadIdx.x;
  const int lane = tid & 63;
  const int wave = tid >> 6;            // 0..7
  const int wr = wave >> 1, wc = wave & 1;
  const long z = blockIdx.z;
  int kstart = 0;
  long zz = z;
  if (KSPLIT > 1) {
    kstart = (int)(z % KSPLIT) * K;
    zz = z / KSPLIT;
  }
  A += zz * aoffz;
  Bt += zz * boffz;

  int bx, by;
  if (SWZ) {
    const int mtiles = M >> 7;
    const int per = mtiles >> 3;          // m-tiles per XCD band
    const int bid = (int)blockIdx.x;
    const int xcd = bid & 7;
    const int slot = bid >> 3;
    by = xcd * per + (slot % per);
    bx = slot / per;
  } else {
    bx = blockIdx.x;
    by = blockIdx.y;
    if (CAUSAL) by = (int)gridDim.y - 1 - by;   // heavy tiles first
  }
  const int m0 = by * 128, n0 = bx * 128;
  int kend = kstart + K;
  if (CAUSAL) {
    int klim = (by + 1) * 128;
    if (klim < kend) kend = klim;
  }

  // Staging: 512 chunks of 16B per 128x32 tile; 1 chunk/thread/matrix.
  // chunk tid -> row srow = tid>>2, slot sc = tid&3; src logical chunk
  // sc ^ ((srow>>1)&3).
  const int srow = tid >> 2, sc = tid & 3;
  const int scol = (sc ^ ((srow >> 1) & 3)) * 8;
  const size_t a0 = (size_t)(m0 + srow) * lda + scol;
  const size_t b0 = (size_t)(n0 + srow) * ldb + scol;

  floatx4 acc[2][4] = {};
  const int fm = lane & 15, fq = lane >> 4;
  const int gph = (fm >> 1) & 3;
  const int nt = (kend - kstart) >> 5;

  auto stage = [&](int buf, int t) {
    const int k0 = kstart + t * 32;
    async16(&A[a0 + k0], &As[buf][tid * 8]);
    async16(&Bt[b0 + k0], &Bs[buf][tid * 8]);
  };

  stage(0, 0);
  if (nt > 1) {
    stage(1, 1);
    asm volatile("s_waitcnt vmcnt(2)" ::: "memory");
  } else {
    asm volatile("s_waitcnt vmcnt(0)" ::: "memory");
  }
  asm volatile("s_barrier" ::: "memory");

  int bufc = 0;
  for (int t = 0; t < nt; t++) {
    int bufn = bufc + 2; if (bufn >= 3) bufn -= 3;
    if (t + 2 < nt) stage(bufn, t + 2);
    short8 af[2], bfr[4];
#pragma unroll
    for (int i = 0; i < 2; i++) {
      int R = wr * 32 + i * 16 + fm;
      af[i] = *(const short8*)&As[bufc][R * 32 + ((fq ^ gph) << 3)];
    }
#pragma unroll
    for (int j = 0; j < 4; j++) {
      int R = wc * 64 + j * 16 + fm;
      bfr[j] = *(const short8*)&Bs[bufc][R * 32 + ((fq ^ gph) << 3)];
    }
#pragma unroll
    for (int i = 0; i < 2; i++)
#pragma unroll
      for (int j = 0; j < 4; j++)
        acc[i][j] = __builtin_amdgcn_mfma_f32_16x16x32_bf16(af[i], bfr[j], acc[i][j], 0, 0, 0);
    if (t + 2 < nt) asm volatile("s_waitcnt vmcnt(2)" ::: "memory");
    else            asm volatile("s_waitcnt vmcnt(0)" ::: "memory");
    asm volatile("s_barrier" ::: "memory");
    bufc++; if (bufc == 3) bufc = 0;
  }

  const int rm0 = (lane >> 4) * 4, cn = lane & 15;
#pragma unroll
  for (int i = 0; i < 2; i++) {
#pragma unroll
    for (int j = 0; j < 4; j++) {
      int nn = n0 + wc * 64 + j * 16 + cn;
      float bv = bias ? bias[nn] : 0.0f;
#pragma unroll
      for (int r = 0; r < 4; r++) {
        int mm = m0 + wr * 32 + i * 16 + rm0 + r;
        float v = acc[i][j][r] + bv;
        if (MODE == 0) {
          ((bf16*)Cptr)[z * coffz + (long)mm * ldc + nn] = f2bf(v);
        } else if (MODE == 1) {
          long idx = z * coffz + (long)mm * ldc + nn;
          float* Cf = (float*)Cptr;
          if (ACCUM) v += Cf[idx];
          Cf[idx] = v;
        } else {
          long idx = ((long)((mm >> 11) * 1024 + nn)) * 2048 + (mm & 2047);
          ((bf16*)Cptr)[idx] = f2bf(v);
        }
      }
    }
  }
}

// ---------------------------------------------------------------------------
// Fused y GEMM: y[t][d] = sum_s sw_s[t] * (x[t] @ W_sense_s)[d] + sw-wtd bias
// A = xhhl hi third (bf16 x, lda=3072); no A' materialization.
// K' = 3072 = 3 senses x 1024; step t covers sense s = t>>5, x-cols
// ((t*32) & 1023).
// Sense scaling at ACCUMULATOR BOUNDARIES (not per-step): plain MFMA into a
// per-sense partial acc; at t = 31/63/95 fold accT += sw_s[row]*acc (fp32,
// C-frag row = m0+wr*32+i*16+rm0+r -> scale sv{0,1,2}[i][r], preloaded as 8
// float4 reads, compile-time-indexed). ~96 VALU total vs ~4600 for per-step
// scaling (round-13: VALUBusy 40%, gemm_y 92us). Numerically matches the
// reference order (fp32 sense-weighting AFTER the bf16 GEMM).
// Same round-7 structure: 8 waves 32x64, tri-buffer BK=32, vmcnt(2), swizzle.
// Grid 512 = 64 mtiles x 8 ntiles, XCD-banded. Bt2[d][s*1024+k] per-sense.
// ---------------------------------------------------------------------------
__global__ __launch_bounds__(512, 4) void gemm_y(
    const bf16* __restrict__ A, const bf16* __restrict__ Bt,
    const float* __restrict__ bsense, const float* __restrict__ sw,
    bf16* __restrict__ y)
{
  __shared__ __align__(16) bf16 As[3][128 * 32];
  __shared__ __align__(16) bf16 Bs[3][128 * 32];

  const int tid = threadIdx.x;
  const int lane = tid & 63;
  const int wave = tid >> 6;
  const int wr = wave >> 1, wc = wave & 1;

  // mtiles=64, ntiles=8, XCD-banded
  const int bid = (int)blockIdx.x;
  const int xcd = bid & 7;
  const int slot = bid >> 3;
  const int by = xcd * 8 + (slot & 7);
  const int bx = slot >> 3;
  const int m0 = by * 128, n0 = bx * 128;

  const int srow = tid >> 2, sc = tid & 3;
  const int scol = (sc ^ ((srow >> 1) & 3)) * 8;
  const size_t a0 = (size_t)(m0 + srow) * 3072 + scol;   // x hi third
  const size_t b0 = (size_t)(n0 + srow) * 3072 + scol;

  floatx4 acc[2][4] = {};    // current-sense partial
  floatx4 accT[2][4] = {};   // weighted total
  const int fm = lane & 15, fq = lane >> 4;
  const int gph = (fm >> 1) & 3;
  const int rm0 = (lane >> 4) * 4;

  // preload sense weights for this thread's 8 C-fragment rows
  float sv0[2][4], sv1[2][4], sv2[2][4];
#pragma unroll
  for (int i = 0; i < 2; i++)
#pragma unroll
    for (int r = 0; r < 4; r++) {
      const float* sm = sw + (size_t)(m0 + wr * 32 + i * 16 + rm0 + r) * 4;
      float4 v4 = *(const float4*)sm;
      sv0[i][r] = v4.x; sv1[i][r] = v4.y; sv2[i][r] = v4.z;
    }

  auto stage = [&](int buf, int t) {
    const int k0a = (t * 32) & 1023;        // x repeats per sense
    const int k0b = t * 32;                  // B spans full 3072
    async16(&A[a0 + k0a], &As[buf][tid * 8]);
    async16(&Bt[b0 + k0b], &Bs[buf][tid * 8]);
  };

  stage(0, 0);
  stage(1, 1);
  asm volatile("s_waitcnt vmcnt(2)" ::: "memory");
  asm volatile("s_barrier" ::: "memory");

  int bufc = 0;
  for (int t = 0; t < 96; t++) {
    int bufn = bufc + 2; if (bufn >= 3) bufn -= 3;
    if (t + 2 < 96) stage(bufn, t + 2);
    short8 af[2], bfr[4];
#pragma unroll
    for (int i = 0; i < 2; i++) {
      int R = wr * 32 + i * 16 + fm;
      af[i] = *(const short8*)&As[bufc][R * 32 + ((fq ^ gph) << 3)];
    }
#pragma unroll
    for (int j = 0; j < 4; j++) {
      int R = wc * 64 + j * 16 + fm;
      bfr[j] = *(const short8*)&Bs[bufc][R * 32 + ((fq ^ gph) << 3)];
    }
#pragma unroll
    for (int i = 0; i < 2; i++)
#pragma unroll
      for (int j = 0; j < 4; j++)
        acc[i][j] = __builtin_amdgcn_mfma_f32_16x16x32_bf16(af[i], bfr[j], acc[i][j], 0, 0, 0);
    if ((t & 31) == 31) {
      // sense boundary: fold weighted partial into total (fp32), reset acc
      const int s = t >> 5;
#pragma unroll
      for (int i = 0; i < 2; i++)
#pragma unroll
        for (int r = 0; r < 4; r++) {
          float scl = (s == 0) ? sv0[i][r] : (s == 1) ? sv1[i][r] : sv2[i][r];
#pragma unroll
          for (int j = 0; j < 4; j++) {
            accT[i][j][r] += scl * acc[i][j][r];
            acc[i][j][r] = 0.0f;
          }
        }
    }
    if (t + 2 < 96) asm volatile("s_waitcnt vmcnt(2)" ::: "memory");
    else            asm volatile("s_waitcnt vmcnt(0)" ::: "memory");
    asm volatile("s_barrier" ::: "memory");
    bufc++; if (bufc == 3) bufc = 0;
  }

  const int cn = lane & 15;
#pragma unroll
  for (int j = 0; j < 4; j++) {
    int nn = n0 + wc * 64 + j * 16 + cn;
    float bb0 = bsense[nn], bb1 = bsense[1024 + nn], bb2 = bsense[2048 + nn];
#pragma unroll
    for (int i = 0; i < 2; i++) {
#pragma unroll
      for (int r = 0; r < 4; r++) {
        int mm = m0 + wr * 32 + i * 16 + rm0 + r;
        float v = accT[i][j][r] + sv0[i][r] * bb0 + sv1[i][r] * bb1 + sv2[i][r] * bb2;
        y[(size_t)mm * 1024 + nn] = f2bf(v);
      }
    }
  }
}

// ---------------------------------------------------------------------------
// x (fp32, 8192x1024) -> xhhl[t][3072] = [hi | hi | lo]
// ---------------------------------------------------------------------------
__global__ __launch_bounds__(256) void k_split_x3(const float* __restrict__ x,
                                                  bf16* __restrict__ xhhl) {
  long id = (long)blockIdx.x * 256 + threadIdx.x;
  if (id >= 8388608L) return;
  long t = id >> 10;
  int d = (int)(id & 1023);
  float v = x[id];
  bf16 h = f2bf(v);
  bf16 l = f2bf(v - bf2f(h));
  bf16* row = xhhl + t * 3072;
  row[d] = h;
  row[1024 + d] = h;
  row[2048 + d] = l;
}

// ---------------------------------------------------------------------------
// W_sense (fp32, 1024x3072) -> Wsn3[s][d][3072] = [hi | lo | hi]
// ---------------------------------------------------------------------------
__global__ __launch_bounds__(256) void k_split_ws3(const float* __restrict__ Ws,
                                                   bf16* __restrict__ Wsn3) {
  long id = (long)blockIdx.x * 256 + threadIdx.x;
  if (id >= 3145728L) return;
  int row10 = (int)(id >> 10);   // = d*3 + s
  int d = row10 / 3;
  int s = row10 - d * 3;
  int dp = (int)(id & 1023);
  float v = Ws[id];
  bf16 h = f2bf(v);
  bf16 l = f2bf(v - bf2f(h));
  bf16* row = Wsn3 + ((size_t)(s * 1024 + d)) * 3072;
  row[dp] = h;
  row[1024 + dp] = l;
  row[2048 + dp] = h;
}

// ---------------------------------------------------------------------------
// Transpose fp32 src[R][C] -> bf16 dh[C][R]
// ---------------------------------------------------------------------------
__global__ __launch_bounds__(256) void k_trans_hl(const float* __restrict__ src,
                                                  bf16* __restrict__ dh,
                                                  int R, int C) {
  __shared__ float tile[32][33];
  int c0 = blockIdx.x * 32, r0 = blockIdx.y * 32;
  int tx = threadIdx.x & 31, ty = threadIdx.x >> 5;
  for (int rr = ty; rr < 32; rr += 8)
    tile[rr][tx] = src[(size_t)(r0 + rr) * C + c0 + tx];
  __syncthreads();
  for (int rr = ty; rr < 32; rr += 8)
    dh[(size_t)(c0 + rr) * R + r0 + tx] = f2bf(tile[tx][rr]);
}

// ---------------------------------------------------------------------------
// Per-sense transpose: Bt2[d][s*1024+k] = W_sense[k][s*1024+d]  (bf16 hi)
// grid (32, 32, 3)
// ---------------------------------------------------------------------------
__global__ __launch_bounds__(256) void k_trans_sense(const float* __restrict__ Ws,
                                                     bf16* __restrict__ Bt2) {
  __shared__ float tile[32][33];
  int c0 = blockIdx.x * 32, r0 = blockIdx.y * 32, s = blockIdx.z;
  int tx = threadIdx.x & 31, ty = threadIdx.x >> 5;
  for (int rr = ty; rr < 32; rr += 8)
    tile[rr][tx] = Ws[(size_t)(r0 + rr) * 3072 + s * 1024 + c0 + tx];
  __syncthreads();
  for (int rr = ty; rr < 32; rr += 8)
    Bt2[(size_t)(c0 + rr) * 3072 + s * 1024 + r0 + tx] = f2bf(tile[tx][rr]);
}

// ---------------------------------------------------------------------------
// Pack head weights -> Whhl3[c][3072] = [hi | hi | lo]; bhead[37]; csig[1024]
// ---------------------------------------------------------------------------
__global__ __launch_bounds__(256) void k_pack(
    const float* __restrict__ W_charge, const float* __restrict__ W_shell,
    const float* __restrict__ W_class, const float* __restrict__ W_mass,
    const float* __restrict__ b_charge, const float* __restrict__ b_shell,
    const float* __restrict__ b_class, const float* __restrict__ b_mass,
    const float* __restrict__ compat_logits,
    bf16* __restrict__ Whhl3, float* __restrict__ bhead, float* __restrict__ csig)
{
  int c = blockIdx.x;
  int tid = threadIdx.x;
  for (int e = tid; e < 1024; e += 256) {
    float v;
    if (c == 0) v = W_charge[e];
    else if (c < 4) v = W_shell[e * 3 + (c - 1)];
    else if (c == 4) v = W_mass[e];
    else if (c < 37) v = W_class[e * 32 + (c - 5)];
    else v = 0.0f;
    bf16 h = f2bf(v);
    bf16 l = f2bf(v - bf2f(h));
    bf16* row = Whhl3 + (size_t)c * 3072;
    row[e] = h;
    row[1024 + e] = h;
    row[2048 + e] = l;
  }
  if (c == 0 && tid < 37) {
    float v;
    if (tid == 0) v = b_charge[0];
    else if (tid < 4) v = b_shell[tid - 1];
    else if (tid == 4) v = b_mass[0];
    else v = b_class[tid - 5];
    bhead[tid] = v;
  }
  if (c == 1) {
    for (int k = tid; k < 1024; k += 256) {
      int ii = k >> 5, jj = k & 31;
      float l = 0.5f * (compat_logits[ii * 32 + jj] + compat_logits[jj * 32 + ii]);
      csig[k] = 1.0f / (1.0f + expf(-l));
    }
  }
}

// ---------------------------------------------------------------------------
// bh[s][c] = b_sense_s . W_head_col_c  (exact fp32)
// ---------------------------------------------------------------------------
__global__ __launch_bounds__(256) void k_bh(
    const float* __restrict__ b_sense, const float* __restrict__ W_charge,
    const float* __restrict__ W_shell, const float* __restrict__ W_class,
    const float* __restrict__ W_mass, float* __restrict__ bh)
{
  const int c = blockIdx.x, s = blockIdx.y;
  const int tid = threadIdx.x;
  __shared__ float red[256];
  float p = 0.0f;
  for (int e = tid; e < 1024; e += 256) {
    float w;
    if (c == 0) w = W_charge[e];
    else if (c < 4) w = W_shell[e * 3 + (c - 1)];
    else if (c == 4) w = W_mass[e];
    else w = W_class[e * 32 + (c - 5)];
    p += b_sense[s * 1024 + e] * w;
  }
  red[tid] = p;
  __syncthreads();
  for (int st = 128; st > 0; st >>= 1) {
    if (tid < st) red[tid] += red[tid + st];
    __syncthreads();
  }
  if (tid == 0) bh[s * 128 + c] = red[0];
}

// ---------------------------------------------------------------------------
// Mt partial reduce: Mt[s][i] = sum_kc Mtp[s*8+kc][i]
// ---------------------------------------------------------------------------
__global__ __launch_bounds__(256) void k_reduce_mt(const float* __restrict__ Mtp,
                                                   float* __restrict__ Mt) {
  long o = (long)blockIdx.x * 256 + threadIdx.x;
  if (o >= 393216L) return;
  long s = o >> 17;
  long i = o & 131071;
  const float* p = Mtp + s * 8 * 131072 + i;
  float acc = 0.0f;
#pragma unroll
  for (int kc = 0; kc < 8; kc++) acc += p[(size_t)kc * 131072];
  Mt[o] = acc;
}

// ---------------------------------------------------------------------------
// Mt (fp32 [3][128][1024]) + W_sel -> Mthl[512][3072] = [hi | lo | hi]
// ---------------------------------------------------------------------------
__global__ __launch_bounds__(256) void k_split(const float* __restrict__ Mt,
                                               const float* __restrict__ W_sel,
                                               bf16* __restrict__ Mthl) {
  long id = (long)blockIdx.x * 256 + threadIdx.x;   // 512*3072
  if (id >= 1572864L) return;
  int n = (int)(id / 3072);
  int k = (int)(id - (long)n * 3072);
  int third = k >> 10;
  int j = k & 1023;
  float v;
  if (n < 384) {
    v = Mt[(size_t)n * 1024 + j];
  } else {
    int c2 = n - 384;
    v = (c2 < 3) ? W_sel[(size_t)j * 3 + c2] : 0.0f;
  }
  bf16 h = f2bf(v);
  Mthl[id] = (third == 1) ? f2bf(v - bf2f(h)) : h;
}

// ---------------------------------------------------------------------------
// xbar[b][d] = mean_n x[b][n][d]
// ---------------------------------------------------------------------------
__global__ __launch_bounds__(256) void k_xbar(const float* __restrict__ x, float* __restrict__ xbar) {
  const int d = blockIdx.x * 256 + threadIdx.x;
  const int b = blockIdx.y;
  const int n0 = blockIdx.z * 256;
  const float* xb = x + (size_t)b * 2048 * 1024 + (size_t)n0 * 1024 + d;
  float s = 0.0f;
  for (int n = 0; n < 256; n++) s += xb[(size_t)n * 1024];
  atomicAdd(&xbar[b * 1024 + d], s * (1.0f / 2048.0f));
}

// ---------------------------------------------------------------------------
// q[e][s] = sum_d W_ctx[e][d]*W_sel[1024+d][s]; q[1024][s] from b_ctx
// ---------------------------------------------------------------------------
__global__ __launch_bounds__(256) void k_q(const float* __restrict__ W_ctx,
                                           const float* __restrict__ b_ctx,
                                           const float* __restrict__ W_sel,
                                           float* __restrict__ q) {
  const int e = blockIdx.x;
  const int tid = threadIdx.x;
  const float* row = (e < 1024) ? (W_ctx + (size_t)e * 1024) : b_ctx;
  float p0 = 0.0f, p1 = 0.0f, p2 = 0.0f;
  for (int d = tid; d < 1024; d += 256) {
    float v = row[d];
    const float* ws = W_sel + (size_t)(1024 + d) * 3;
    p0 += v * ws[0]; p1 += v * ws[1]; p2 += v * ws[2];
  }
  __shared__ float red[3][256];
  red[0][tid] = p0; red[1][tid] = p1; red[2][tid] = p2;
  __syncthreads();
  for (int st = 128; st > 0; st >>= 1) {
    if (tid < st) {
      red[0][tid] += red[0][tid + st];
      red[1][tid] += red[1][tid + st];
      red[2][tid] += red[2][tid + st];
    }
    __syncthreads();
  }
  if (tid < 3) q[(size_t)e * 3 + tid] = red[tid][0];
}

// ---------------------------------------------------------------------------
__global__ __launch_bounds__(256) void k_ctxsel(const float* __restrict__ xbar,
                                                const float* __restrict__ q,
                                                float* __restrict__ ctx_sel) {
  const int b = blockIdx.x;
  const int tid = threadIdx.x;
  float p0 = 0.0f, p1 = 0.0f, p2 = 0.0f;
  for (int e = tid; e < 1024; e += 256) {
    float v = xbar[b * 1024 + e];
    p0 += v * q[e * 3 + 0]; p1 += v * q[e * 3 + 1]; p2 += v * q[e * 3 + 2];
  }
  __shared__ float red[3][256];
  red[0][tid] = p0; red[1][tid] = p1; red[2][tid] = p2;
  __syncthreads();
  for (int st = 128; st > 0; st >>= 1) {
    if (tid < st) {
      red[0][tid] += red[0][tid + st];
      red[1][tid] += red[1][tid + st];
      red[2][tid] += red[2][tid + st];
    }
    __syncthreads();
  }
  if (tid < 3) ctx_sel[b * 3 + tid] = red[tid][0] + q[1024 * 3 + tid];
}

// ---------------------------------------------------------------------------
// Per token: sense softmax weights -> sw[t][4]; head features -> feat[t][8]
// 4 tokens per 256-thread block (64-lane groups). H = 2 split-K planes.
// ---------------------------------------------------------------------------
__global__ __launch_bounds__(256) void k_heads(
    const float* __restrict__ H, const float* __restrict__ ctx_sel,
    const float* __restrict__ b_sel, const float* __restrict__ bh,
    const float* __restrict__ bhead,
    float* __restrict__ sw, float* __restrict__ feat)
{
  const int g = threadIdx.x >> 6;
  const int lane = threadIdx.x & 63;
  const int t = blockIdx.x * 4 + g;
  const int b = t >> 11;
  const float* Ht = H + (size_t)t * 512;
  const float* Ht2 = H + 4194304 + (size_t)t * 512;

  float s0 = Ht[384] + Ht2[384] + ctx_sel[b * 3 + 0] + b_sel[0];
  float s1 = Ht[385] + Ht2[385] + ctx_sel[b * 3 + 1] + b_sel[1];
  float s2 = Ht[386] + Ht2[386] + ctx_sel[b * 3 + 2] + b_sel[2];
  float mx = fmaxf(s0, fmaxf(s1, s2));
  float e0 = expf(s0 - mx), e1 = expf(s1 - mx), e2 = expf(s2 - mx);
  float inv = 1.0f / (e0 + e1 + e2);
  float w0 = e0 * inv, w1 = e1 * inv, w2 = e2 * inv;

  __shared__ float L[4][64];
  if (lane < 37) {
    float lg = bhead[lane];
    lg += w0 * (Ht[lane] + Ht2[lane] + bh[lane]);
    lg += w1 * (Ht[128 + lane] + Ht2[128 + lane] + bh[128 + lane]);
    lg += w2 * (Ht[256 + lane] + Ht2[256 + lane] + bh[256 + lane]);
    L[g][lane] = lg;
  }
  __syncthreads();
  if (lane == 0) {
    float charge = tanhf(L[g][0]);
    float h0 = L[g][1], h1 = L[g][2], h2 = L[g][3];
    float hm = fmaxf(h0, fmaxf(h1, h2));
    float x0 = expf(h0 - hm), x1 = expf(h1 - hm), x2 = expf(h2 - hm);
    float hinv = 1.0f / (x0 + x1 + x2);
    float mass = softplusf(L[g][4]) + 0.5f;
    int cls = 0;
    float best = L[g][5];
    for (int c = 1; c < 32; c++) {
      if (L[g][5 + c] > best) { best = L[g][5 + c]; cls = c; }
    }
    float* f = feat + (size_t)t * 8;
    f[0] = charge; f[1] = mass;
    f[2] = x0 * hinv; f[3] = x1 * hinv; f[4] = x2 * hinv;
    f[5] = (float)cls; f[6] = 0.0f; f[7] = 0.0f;
    float* sp_ = sw + (size_t)t * 4;
    sp_[0] = w0; sp_[1] = w1; sp_[2] = w2; sp_[3] = 0.0f;
  }
}

// ---------------------------------------------------------------------------
__global__ __launch_bounds__(256) void k_scores(
    const float* __restrict__ feat, const float* __restrict__ compat,
    const float* __restrict__ wchg, const float* __restrict__ wsh,
    const float* __restrict__ wdist, const float* __restrict__ wmass,
    const float* __restrict__ wval, const float* __restrict__ temp_p,
    bf16* __restrict__ P)
{
  const int i = blockIdx.x, b = blockIdx.y;
  const int tid = threadIdx.x;
  __shared__ float cs[1024];
  __shared__ float red[256];
  for (int k = tid; k < 1024; k += 256) cs[k] = compat[k];
  __syncthreads();

  const float a = softplusf(wchg[0]);
  const float bs = softplusf(wsh[0]);
  const float c = softplusf(wdist[0]);
  const float dm = softplusf(wmass[0]);
  const float ev = softplusf(wval[0]);
  const float itmp = 1.0f / softplusf(temp_p[0]);

  const float4* fi4 = (const float4*)(feat + ((size_t)b * 2048 + i) * 8);
  float4 fiA = fi4[0], fiB = fi4[1];
  const float ci = fiA.x, mi = fiA.y, si0 = fiA.z, si1 = fiA.w, si2 = fiB.x;
  int cli = (int)fiB.y; cli = cli < 0 ? 0 : (cli > 31 ? 31 : cli);

  float sc[8];
  float lmax = -3.0e38f;
#pragma unroll
  for (int jj = 0; jj < 8; jj++) {
    int j = tid + jj * 256;
    const float4* fj4 = (const float4*)(feat + ((size_t)b * 2048 + j) * 8);
    float4 fjA = fj4[0], fjB = fj4[1];
    int clj = (int)fjB.y; clj = clj < 0 ? 0 : (clj > 31 ? 31 : clj);
    float E = a * ci * fjA.x
            + bs * (fabsf(si0 - fjA.z) + fabsf(si1 - fjA.w) + fabsf(si2 - fjB.x))
            - c / (1.0f + 0.1f * fabsf((float)(i - j)))
            + dm * 0.1f * mi * fjA.y
            - ev;
    float s = (j <= i) ? (-E * itmp) * cs[cli * 32 + clj] : -3.0e38f;
    sc[jj] = s;
    lmax = fmaxf(lmax, s);
  }
  red[tid] = lmax;
  __syncthreads();
  for (int st = 128; st > 0; st >>= 1) {
    if (tid < st) red[tid] = fmaxf(red[tid], red[tid + st]);
    __syncthreads();
  }
  const float mrow = red[0];
  __syncthreads();

  float pv[8];
  float lsum = 0.0f;
#pragma unroll
  for (int jj = 0; jj < 8; jj++) {
    pv[jj] = (sc[jj] > -1.0e37f) ? expf(sc[jj] - mrow) : 0.0f;
    lsum += pv[jj];
  }
  red[tid] = lsum;
  __syncthreads();
  for (int st = 128; st > 0; st >>= 1) {
    if (tid < st) red[tid] += red[tid + st];
    __syncthreads();
  }
  const float inv = 1.0f / red[0];
  bf16* Pi = P + ((size_t)b * 2048 + i) * 2048;
#pragma unroll
  for (int jj = 0; jj < 8; jj++) Pi[tid + jj * 256] = f2bf(pv[jj] * inv);
}

// ---------------------------------------------------------------------------
extern "C" void kernel_launch(void* const* d_in, const int* in_sizes, int n_in,
                              void* d_out, int out_size, void* d_ws, size_t ws_size,
                              hipStream_t stream) {
  (void)in_sizes; (void)n_in; (void)out_size; (void)ws_size;
  const float* x        = (const float*)d_in[0];
  const float* W_sense  = (const float*)d_in[1];
  const float* b_sense  = (const float*)d_in[2];
  const float* W_ctx    = (const float*)d_in[3];
  const float* b_ctx    = (const float*)d_in[4];
  const float* W_sel    = (const float*)d_in[5];
  const float* b_sel    = (const float*)d_in[6];
  const float* W_charge = (const float*)d_in[7];
  const float* b_charge = (const float*)d_in[8];
  const float* W_shell  = (const float*)d_in[9];
  const float* b_shell  = (const float*)d_in[10];
  const float* W_class  = (const float*)d_in[11];
  const float* b_class  = (const float*)d_in[12];
  const float* W_mass   = (const float*)d_in[13];
  const float* b_mass   = (const float*)d_in[14];
  const float* compat_logits = (const float*)d_in[17];
  const float* w_charge = (const float*)d_in[18];
  const float* w_shell  = (const float*)d_in[19];
  const float* w_distance = (const float*)d_in[20];
  const float* w_mass   = (const float*)d_in[21];
  const float* w_valence = (const float*)d_in[22];
  const float* temperature = (const float*)d_in[23];
  const float* W_v      = (const float*)d_in[24];
  const float* b_v      = (const float*)d_in[25];
  const float* W_out    = (const float*)d_in[26];
  const float* b_out    = (const float*)d_in[27];

  char* w = (char*)d_ws;
  auto alloc = [&](size_t bytes) {
    char* p = w;
    w += (bytes + 255) & ~(size_t)255;
    return p;
  };
  bf16* xhhl  = (bf16*)alloc(8192ULL * 3072 * 2);
  char* R1    = alloc(48ULL * 1024 * 1024);
  bf16* Wsn3  = (bf16*)R1;
  float* Hh   = (float*)R1;
  float* Mtp  = (float*)(R1 + 20ULL * 1024 * 1024);      // [24][131072] fp32
  bf16* Mthl  = (bf16*)(R1 + 40ULL * 1024 * 1024);       // [512][3072] bf16
  float* Mt   = (float*)(R1 + 44ULL * 1024 * 1024);      // [3][128][1024] fp32
  bf16* y     = (bf16*)R1;                               // [8192][1024] bf16
  bf16* Wts2  = (bf16*)alloc(3072ULL * 1024 * 2);        // Bt2 [1024][3072]
  bf16* Wt_v  = (bf16*)alloc(1024ULL * 1024 * 2);
  bf16* Wt_out = (bf16*)alloc(1024ULL * 1024 * 2);
  bf16* Whhl3 = (bf16*)alloc(128ULL * 3072 * 2);
  float* bh   = (float*)alloc(3ULL * 128 * 4);
  float* bhead = (float*)alloc(256);
  float* csig = (float*)alloc(4096);
  float* xbar = (float*)alloc(4ULL * 1024 * 4);
  float* qbuf = (float*)alloc(1025ULL * 3 * 4);
  float* ctx_sel = (float*)alloc(256);
  float* feat = (float*)alloc(8192ULL * 8 * 4);
  float* sw   = (float*)alloc(8192ULL * 4 * 4);
  // aliases inside xhhl (48 MB flat); Vt/O written only after gemm_y is done
  bf16* Vt = xhhl + 8388608;          // 16 MB
  bf16* O  = xhhl + 16777216;         // 16 MB
  bf16* P  = (bf16*)d_out;            // 32 MiB; consumed before final GEMM

  // ---- input conversions ----
  k_split_x3<<<32768, 256, 0, stream>>>(x, xhhl);
  k_split_ws3<<<12288, 256, 0, stream>>>(W_sense, Wsn3);
  k_trans_sense<<<dim3(32, 32, 3), 256, 0, stream>>>(W_sense, Wts2);
  k_trans_hl<<<dim3(32, 32), 256, 0, stream>>>(W_v, Wt_v, 1024, 1024);
  k_trans_hl<<<dim3(32, 32), 256, 0, stream>>>(W_out, Wt_out, 1024, 1024);
  k_pack<<<128, 256, 0, stream>>>(W_charge, W_shell, W_class, W_mass,
                                  b_charge, b_shell, b_class, b_mass,
                                  compat_logits, Whhl3, bhead, csig);

  // ---- ctx path ----
  hipMemsetAsync(xbar, 0, 4096 * 4, stream);
  k_xbar<<<dim3(4, 4, 8), 256, 0, stream>>>(x, xbar);
  k_q<<<1025, 256, 0, stream>>>(W_ctx, b_ctx, W_sel, qbuf);
  k_ctxsel<<<4, 256, 0, stream>>>(xbar, qbuf, ctx_sel);

  // ---- Mt fold: 8-way K-split (chunk=384) -> 192 blocks, then reduce ----
  gemm_bt<1, 0, 0, 0, 8><<<dim3(8, 1, 24), 512, 0, stream>>>(
      Whhl3, Wsn3, nullptr, Mtp, 128, 1024, 384, 3072, 3072, 1024,
      0, 3145728L, 131072L);
  k_reduce_mt<<<1536, 256, 0, stream>>>(Mtp, Mt);
  k_split<<<6144, 256, 0, stream>>>(Mt, W_sel, Mthl);

  // ---- H = x @ [Mt | Wsel]^T, 2-way K-split (chunk=1536) -> 512 blocks ----
  gemm_bt<1, 0, 0, 1, 2><<<dim3(256, 1, 2), 512, 0, stream>>>(
      xhhl, Mthl, nullptr, Hh, 8192, 512, 1536, 3072, 3072, 512,
      0, 0, 4194304L);

  // ---- bh (exact fp32) + per-token heads (sums the 2 H planes) ----
  k_bh<<<dim3(37, 3), 256, 0, stream>>>(b_sense, W_charge, W_shell, W_class, W_mass, bh);
  k_heads<<<2048, 256, 0, stream>>>(Hh, ctx_sel, b_sel, bh, bhead, sw, feat);

  // ---- y = sum_s sw_s*(x @ W_sense_s) + sw-wtd bias (boundary-scaled) ----
  gemm_y<<<512, 512, 0, stream>>>(xhhl, Wts2, b_sense, sw, y);

  // ---- V^T (batched): Vt[b][d][n] ----
  gemm_bt<2, 0, 0, 1><<<512, 512, 0, stream>>>(
      y, Wt_v, b_v, Vt, 8192, 1024, 1024, 1024, 1024, 0, 0, 0, 0);

  // ---- P = causal softmax of pair scores (in d_out) ----
  k_scores<<<dim3(2048, 4), 256, 0, stream>>>(feat, csig, w_charge, w_shell,
                                              w_distance, w_mass, w_valence, temperature, P);

  // ---- O = P @ V (causal k-limit, heavy-first), per batch ----
  gemm_bt<0, 1, 0, 0><<<dim3(8, 16, 4), 512, 0, stream>>>(
      P, Vt, nullptr, O, 2048, 1024, 2048, 2048, 2048, 1024,
      2048L * 2048, 1024L * 2048, 2048L * 1024);

  // ---- out = O @ W_out + b_out (fp32, overwrites P) ----
  gemm_bt<1, 0, 0, 1><<<512, 512, 0, stream>>>(
      O, Wt_out, b_out, (float*)d_out, 8192, 1024, 1024, 1024, 1024, 1024, 0, 0, 0);
}

// Round 16
// 487.013 us; speedup vs baseline: 1.1426x; 1.0330x over previous
//
#include <hip/hip_runtime.h>
#include <hip/hip_bf16.h>
#include <cmath>

typedef __hip_bfloat16 bf16;
typedef __attribute__((ext_vector_type(4))) float floatx4;
typedef __attribute__((ext_vector_type(8))) short short8;
typedef __attribute__((ext_vector_type(8))) unsigned short ushort8;

__device__ __forceinline__ float bf2f(bf16 v) { return __bfloat162float(v); }
__device__ __forceinline__ bf16 f2bf(float v) { return __float2bfloat16(v); }
__device__ __forceinline__ float bfu2f(unsigned short u) { return __uint_as_float(((unsigned)u) << 16); }
__device__ __forceinline__ unsigned short f2bfu(float v) {
  bf16 h = __float2bfloat16(v);
  return __builtin_bit_cast(unsigned short, h);
}
__device__ __forceinline__ float softplusf(float x) {
  return x > 20.0f ? x : log1pf(expf(x));
}

__device__ __forceinline__ void async16(const void* g, void* l) {
  __builtin_amdgcn_global_load_lds(
      (const __attribute__((address_space(1))) unsigned int*)g,
      (__attribute__((address_space(3))) unsigned int*)l, 16, 0, 0);
}

// ---------------------------------------------------------------------------
// Generic bf16 GEMM: C[m][n] = sum_k A[m][k] * Bt[n][k]  (+ fp32 bias[n])
// [round-7/14 measured config: gemm family MfmaUtil ~27%, 16 waves/CU]
// 512 threads / 8 waves per block over a 128x128 tile (wave = 32x64 out:
// 2x4 frags of 16x16x32). Tri-buffered BK=32 with COUNTED vmcnt: at step t
// issue loads for tile t+2 (1 chunk/thread/matrix), compute tile t, then
// s_waitcnt vmcnt(2) (t+1's 2 loads per wave) + raw s_barrier. 48KB LDS ->
// 2 blocks/CU = 16 waves/CU (launch_bounds(512,4)).
// LDS swizzle (both-sides involution): physical 16B chunk c of row r holds
// logical chunk c ^ ((r>>1)&3); staged via pre-swizzled global source col.
// Read side: gph = (fm>>1)&3 == (R>>1)&3 because wr*32, wc*64, i*16 = 0 mod 4.
// MODE 0: bf16 out row-major (ldc).   MODE 1: fp32 out (ldc), ACCUM adds.
// MODE 2: bf16 out transposed-batched: Vt[(m>>11)*1024 + n][m&2047].
//         Round-14 analysis: direct per-lane 8B stores at 4KB lane stride =
//         ~8x HBM write amplification. Fixed via LDS-transposed epilogue:
//         scatter acc+bias into [128][132]-padded bf16 tile in the (dead)
//         staging LDS, sync, write coalesced 16B/lane rows.
// CAUSAL: k limited to (m_tile+1)*128; m-tiles issued heavy-first.
// SWZ: flat grid.x = mtiles*ntiles; XCD-banded decode (bid&7 -> m band).
// KSPLIT>1: z = zz*KSPLIT + kc; K is the CHUNK length, kstart = kc*K.
// All K chunks must be multiples of 32.
// ---------------------------------------------------------------------------
template<int MODE, int CAUSAL, int ACCUM, int SWZ, int KSPLIT = 1>
__global__ __launch_bounds__(512, 4) void gemm_bt(
    const bf16* __restrict__ A, const bf16* __restrict__ Bt,
    const float* __restrict__ bias, void* __restrict__ Cptr,
    int M, int N, int K, int lda, int ldb, int ldc,
    long aoffz, long boffz, long coffz)
{
  __shared__ __align__(16) bf16 smem[6][128 * 32];   // As=smem[0..2], Bs=smem[3..5]
  bf16 (*As)[128 * 32] = &smem[0];
  bf16 (*Bs)[128 * 32] = &smem[3];

  const int tid = threadIdx.x;
  const int lane = tid & 63;
  const int wave = tid >> 6;            // 0..7
  const int wr = wave >> 1, wc = wave & 1;
  const long z = blockIdx.z;
  int kstart = 0;
  long zz = z;
  if (KSPLIT > 1) {
    kstart = (int)(z % KSPLIT) * K;
    zz = z / KSPLIT;
  }
  A += zz * aoffz;
  Bt += zz * boffz;

  int bx, by;
  if (SWZ) {
    const int mtiles = M >> 7;
    const int per = mtiles >> 3;          // m-tiles per XCD band
    const int bid = (int)blockIdx.x;
    const int xcd = bid & 7;
    const int slot = bid >> 3;
    by = xcd * per + (slot % per);
    bx = slot / per;
  } else {
    bx = blockIdx.x;
    by = blockIdx.y;
    if (CAUSAL) by = (int)gridDim.y - 1 - by;   // heavy tiles first
  }
  const int m0 = by * 128, n0 = bx * 128;
  int kend = kstart + K;
  if (CAUSAL) {
    int klim = (by + 1) * 128;
    if (klim < kend) kend = klim;
  }

  // Staging: 512 chunks of 16B per 128x32 tile; 1 chunk/thread/matrix.
  // chunk tid -> row srow = tid>>2, slot sc = tid&3; src logical chunk
  // sc ^ ((srow>>1)&3).
  const int srow = tid >> 2, sc = tid & 3;
  const int scol = (sc ^ ((srow >> 1) & 3)) * 8;
  const size_t a0 = (size_t)(m0 + srow) * lda + scol;
  const size_t b0 = (size_t)(n0 + srow) * ldb + scol;

  floatx4 acc[2][4] = {};
  const int fm = lane & 15, fq = lane >> 4;
  const int gph = (fm >> 1) & 3;
  const int nt = (kend - kstart) >> 5;

  auto stage = [&](int buf, int t) {
    const int k0 = kstart + t * 32;
    async16(&A[a0 + k0], &As[buf][tid * 8]);
    async16(&Bt[b0 + k0], &Bs[buf][tid * 8]);
  };

  stage(0, 0);
  if (nt > 1) {
    stage(1, 1);
    asm volatile("s_waitcnt vmcnt(2)" ::: "memory");
  } else {
    asm volatile("s_waitcnt vmcnt(0)" ::: "memory");
  }
  asm volatile("s_barrier" ::: "memory");

  int bufc = 0;
  for (int t = 0; t < nt; t++) {
    int bufn = bufc + 2; if (bufn >= 3) bufn -= 3;
    if (t + 2 < nt) stage(bufn, t + 2);
    short8 af[2], bfr[4];
#pragma unroll
    for (int i = 0; i < 2; i++) {
      int R = wr * 32 + i * 16 + fm;
      af[i] = *(const short8*)&As[bufc][R * 32 + ((fq ^ gph) << 3)];
    }
#pragma unroll
    for (int j = 0; j < 4; j++) {
      int R = wc * 64 + j * 16 + fm;
      bfr[j] = *(const short8*)&Bs[bufc][R * 32 + ((fq ^ gph) << 3)];
    }
#pragma unroll
    for (int i = 0; i < 2; i++)
#pragma unroll
      for (int j = 0; j < 4; j++)
        acc[i][j] = __builtin_amdgcn_mfma_f32_16x16x32_bf16(af[i], bfr[j], acc[i][j], 0, 0, 0);
    if (t + 2 < nt) asm volatile("s_waitcnt vmcnt(2)" ::: "memory");
    else            asm volatile("s_waitcnt vmcnt(0)" ::: "memory");
    asm volatile("s_barrier" ::: "memory");
    bufc++; if (bufc == 3) bufc = 0;
  }

  const int rm0 = (lane >> 4) * 4, cn = lane & 15;
  if constexpr (MODE == 2) {
    // LDS-transposed epilogue: staging LDS is dead past the final barrier.
    bf16* T = &smem[0][0];                 // [128 nn][stride 132] bf16, 33.8KB
#pragma unroll
    for (int i = 0; i < 2; i++)
#pragma unroll
      for (int j = 0; j < 4; j++) {
        int nn_l = wc * 64 + j * 16 + cn;
        float bv = bias ? bias[n0 + nn_l] : 0.0f;
#pragma unroll
        for (int r = 0; r < 4; r++) {
          int mm_l = wr * 32 + i * 16 + rm0 + r;
          T[nn_l * 132 + mm_l] = f2bf(acc[i][j][r] + bv);
        }
      }
    __syncthreads();
    const int bb = m0 >> 11, nb = m0 & 2047;
#pragma unroll
    for (int c4 = 0; c4 < 4; c4++) {
      int c = tid + c4 * 512;              // 2048 chunks of 8 bf16
      int row = c >> 4, col = (c & 15) << 3;
      ushort8 v8;
#pragma unroll
      for (int e = 0; e < 8; e++)
        v8[e] = __builtin_bit_cast(unsigned short, T[row * 132 + col + e]);
      *(ushort8*)&((bf16*)Cptr)[((size_t)(bb * 1024 + n0 + row)) * 2048 + nb + col] = v8;
    }
  } else {
#pragma unroll
    for (int i = 0; i < 2; i++) {
#pragma unroll
      for (int j = 0; j < 4; j++) {
        int nn = n0 + wc * 64 + j * 16 + cn;
        float bv = bias ? bias[nn] : 0.0f;
#pragma unroll
        for (int r = 0; r < 4; r++) {
          int mm = m0 + wr * 32 + i * 16 + rm0 + r;
          float v = acc[i][j][r] + bv;
          if (MODE == 0) {
            ((bf16*)Cptr)[z * coffz + (long)mm * ldc + nn] = f2bf(v);
          } else {
            long idx = z * coffz + (long)mm * ldc + nn;
            float* Cf = (float*)Cptr;
            if (ACCUM) v += Cf[idx];
            Cf[idx] = v;
          }
        }
      }
    }
  }
}

// ---------------------------------------------------------------------------
// Fused y GEMM: y[t][d] = sum_s sw_s[t] * (x[t] @ W_sense_s)[d] + sw-wtd bias
// A = xhhl hi third (bf16 x, lda=3072); no A' materialization.
// K' = 3072 = 3 senses x 1024; step t covers sense s = t>>5, x-cols
// ((t*32) & 1023).
// Sense scaling at ACCUMULATOR BOUNDARIES: plain MFMA into per-sense acc;
// at t = 31/63/95 fold accT += sw_s[row]*acc. [round-14 measured: 79.8us,
// MfmaUtil 26.6, VALUBusy 17.8 — scaling off the MFMA critical path]
// Same round-7 structure: 8 waves 32x64, tri-buffer BK=32, vmcnt(2), swizzle.
// Grid 512 = 64 mtiles x 8 ntiles, XCD-banded. Bt2[d][s*1024+k] per-sense.
// ---------------------------------------------------------------------------
__global__ __launch_bounds__(512, 4) void gemm_y(
    const bf16* __restrict__ A, const bf16* __restrict__ Bt,
    const float* __restrict__ bsense, const float* __restrict__ sw,
    bf16* __restrict__ y)
{
  __shared__ __align__(16) bf16 As[3][128 * 32];
  __shared__ __align__(16) bf16 Bs[3][128 * 32];

  const int tid = threadIdx.x;
  const int lane = tid & 63;
  const int wave = tid >> 6;
  const int wr = wave >> 1, wc = wave & 1;

  // mtiles=64, ntiles=8, XCD-banded
  const int bid = (int)blockIdx.x;
  const int xcd = bid & 7;
  const int slot = bid >> 3;
  const int by = xcd * 8 + (slot & 7);
  const int bx = slot >> 3;
  const int m0 = by * 128, n0 = bx * 128;

  const int srow = tid >> 2, sc = tid & 3;
  const int scol = (sc ^ ((srow >> 1) & 3)) * 8;
  const size_t a0 = (size_t)(m0 + srow) * 3072 + scol;   // x hi third
  const size_t b0 = (size_t)(n0 + srow) * 3072 + scol;

  floatx4 acc[2][4] = {};    // current-sense partial
  floatx4 accT[2][4] = {};   // weighted total
  const int fm = lane & 15, fq = lane >> 4;
  const int gph = (fm >> 1) & 3;
  const int rm0 = (lane >> 4) * 4;

  // preload sense weights for this thread's 8 C-fragment rows
  float sv0[2][4], sv1[2][4], sv2[2][4];
#pragma unroll
  for (int i = 0; i < 2; i++)
#pragma unroll
    for (int r = 0; r < 4; r++) {
      const float* sm = sw + (size_t)(m0 + wr * 32 + i * 16 + rm0 + r) * 4;
      float4 v4 = *(const float4*)sm;
      sv0[i][r] = v4.x; sv1[i][r] = v4.y; sv2[i][r] = v4.z;
    }

  auto stage = [&](int buf, int t) {
    const int k0a = (t * 32) & 1023;        // x repeats per sense
    const int k0b = t * 32;                  // B spans full 3072
    async16(&A[a0 + k0a], &As[buf][tid * 8]);
    async16(&Bt[b0 + k0b], &Bs[buf][tid * 8]);
  };

  stage(0, 0);
  stage(1, 1);
  asm volatile("s_waitcnt vmcnt(2)" ::: "memory");
  asm volatile("s_barrier" ::: "memory");

  int bufc = 0;
  for (int t = 0; t < 96; t++) {
    int bufn = bufc + 2; if (bufn >= 3) bufn -= 3;
    if (t + 2 < 96) stage(bufn, t + 2);
    short8 af[2], bfr[4];
#pragma unroll
    for (int i = 0; i < 2; i++) {
      int R = wr * 32 + i * 16 + fm;
      af[i] = *(const short8*)&As[bufc][R * 32 + ((fq ^ gph) << 3)];
    }
#pragma unroll
    for (int j = 0; j < 4; j++) {
      int R = wc * 64 + j * 16 + fm;
      bfr[j] = *(const short8*)&Bs[bufc][R * 32 + ((fq ^ gph) << 3)];
    }
#pragma unroll
    for (int i = 0; i < 2; i++)
#pragma unroll
      for (int j = 0; j < 4; j++)
        acc[i][j] = __builtin_amdgcn_mfma_f32_16x16x32_bf16(af[i], bfr[j], acc[i][j], 0, 0, 0);
    if ((t & 31) == 31) {
      // sense boundary: fold weighted partial into total (fp32), reset acc
      const int s = t >> 5;
#pragma unroll
      for (int i = 0; i < 2; i++)
#pragma unroll
        for (int r = 0; r < 4; r++) {
          float scl = (s == 0) ? sv0[i][r] : (s == 1) ? sv1[i][r] : sv2[i][r];
#pragma unroll
          for (int j = 0; j < 4; j++) {
            accT[i][j][r] += scl * acc[i][j][r];
            acc[i][j][r] = 0.0f;
          }
        }
    }
    if (t + 2 < 96) asm volatile("s_waitcnt vmcnt(2)" ::: "memory");
    else            asm volatile("s_waitcnt vmcnt(0)" ::: "memory");
    asm volatile("s_barrier" ::: "memory");
    bufc++; if (bufc == 3) bufc = 0;
  }

  const int cn = lane & 15;
#pragma unroll
  for (int j = 0; j < 4; j++) {
    int nn = n0 + wc * 64 + j * 16 + cn;
    float bb0 = bsense[nn], bb1 = bsense[1024 + nn], bb2 = bsense[2048 + nn];
#pragma unroll
    for (int i = 0; i < 2; i++) {
#pragma unroll
      for (int r = 0; r < 4; r++) {
        int mm = m0 + wr * 32 + i * 16 + rm0 + r;
        float v = accT[i][j][r] + sv0[i][r] * bb0 + sv1[i][r] * bb1 + sv2[i][r] * bb2;
        y[(size_t)mm * 1024 + nn] = f2bf(v);
      }
    }
  }
}

// ---------------------------------------------------------------------------
// x (fp32, 8192x1024) -> xhhl[t][3072] = [hi | hi | lo]
// ---------------------------------------------------------------------------
__global__ __launch_bounds__(256) void k_split_x3(const float* __restrict__ x,
                                                  bf16* __restrict__ xhhl) {
  long id = (long)blockIdx.x * 256 + threadIdx.x;
  if (id >= 8388608L) return;
  long t = id >> 10;
  int d = (int)(id & 1023);
  float v = x[id];
  bf16 h = f2bf(v);
  bf16 l = f2bf(v - bf2f(h));
  bf16* row = xhhl + t * 3072;
  row[d] = h;
  row[1024 + d] = h;
  row[2048 + d] = l;
}

// ---------------------------------------------------------------------------
// W_sense (fp32, 1024x3072) -> Wsn3[s][d][3072] = [hi | lo | hi]
// ---------------------------------------------------------------------------
__global__ __launch_bounds__(256) void k_split_ws3(const float* __restrict__ Ws,
                                                   bf16* __restrict__ Wsn3) {
  long id = (long)blockIdx.x * 256 + threadIdx.x;
  if (id >= 3145728L) return;
  int row10 = (int)(id >> 10);   // = d*3 + s
  int d = row10 / 3;
  int s = row10 - d * 3;
  int dp = (int)(id & 1023);
  float v = Ws[id];
  bf16 h = f2bf(v);
  bf16 l = f2bf(v - bf2f(h));
  bf16* row = Wsn3 + ((size_t)(s * 1024 + d)) * 3072;
  row[dp] = h;
  row[1024 + dp] = l;
  row[2048 + dp] = h;
}

// ---------------------------------------------------------------------------
// Transpose fp32 src[R][C] -> bf16 dh[C][R]
// ---------------------------------------------------------------------------
__global__ __launch_bounds__(256) void k_trans_hl(const float* __restrict__ src,
                                                  bf16* __restrict__ dh,
                                                  int R, int C) {
  __shared__ float tile[32][33];
  int c0 = blockIdx.x * 32, r0 = blockIdx.y * 32;
  int tx = threadIdx.x & 31, ty = threadIdx.x >> 5;
  for (int rr = ty; rr < 32; rr += 8)
    tile[rr][tx] = src[(size_t)(r0 + rr) * C + c0 + tx];
  __syncthreads();
  for (int rr = ty; rr < 32; rr += 8)
    dh[(size_t)(c0 + rr) * R + r0 + tx] = f2bf(tile[tx][rr]);
}

// ---------------------------------------------------------------------------
// Per-sense transpose: Bt2[d][s*1024+k] = W_sense[k][s*1024+d]  (bf16 hi)
// grid (32, 32, 3)
// ---------------------------------------------------------------------------
__global__ __launch_bounds__(256) void k_trans_sense(const float* __restrict__ Ws,
                                                     bf16* __restrict__ Bt2) {
  __shared__ float tile[32][33];
  int c0 = blockIdx.x * 32, r0 = blockIdx.y * 32, s = blockIdx.z;
  int tx = threadIdx.x & 31, ty = threadIdx.x >> 5;
  for (int rr = ty; rr < 32; rr += 8)
    tile[rr][tx] = Ws[(size_t)(r0 + rr) * 3072 + s * 1024 + c0 + tx];
  __syncthreads();
  for (int rr = ty; rr < 32; rr += 8)
    Bt2[(size_t)(c0 + rr) * 3072 + s * 1024 + r0 + tx] = f2bf(tile[tx][rr]);
}

// ---------------------------------------------------------------------------
// Pack head weights -> Whhl3[c][3072] = [hi | hi | lo]; bhead[37]; csig[1024]
// ---------------------------------------------------------------------------
__global__ __launch_bounds__(256) void k_pack(
    const float* __restrict__ W_charge, const float* __restrict__ W_shell,
    const float* __restrict__ W_class, const float* __restrict__ W_mass,
    const float* __restrict__ b_charge, const float* __restrict__ b_shell,
    const float* __restrict__ b_class, const float* __restrict__ b_mass,
    const float* __restrict__ compat_logits,
    bf16* __restrict__ Whhl3, float* __restrict__ bhead, float* __restrict__ csig)
{
  int c = blockIdx.x;
  int tid = threadIdx.x;
  for (int e = tid; e < 1024; e += 256) {
    float v;
    if (c == 0) v = W_charge[e];
    else if (c < 4) v = W_shell[e * 3 + (c - 1)];
    else if (c == 4) v = W_mass[e];
    else if (c < 37) v = W_class[e * 32 + (c - 5)];
    else v = 0.0f;
    bf16 h = f2bf(v);
    bf16 l = f2bf(v - bf2f(h));
    bf16* row = Whhl3 + (size_t)c * 3072;
    row[e] = h;
    row[1024 + e] = h;
    row[2048 + e] = l;
  }
  if (c == 0 && tid < 37) {
    float v;
    if (tid == 0) v = b_charge[0];
    else if (tid < 4) v = b_shell[tid - 1];
    else if (tid == 4) v = b_mass[0];
    else v = b_class[tid - 5];
    bhead[tid] = v;
  }
  if (c == 1) {
    for (int k = tid; k < 1024; k += 256) {
      int ii = k >> 5, jj = k & 31;
      float l = 0.5f * (compat_logits[ii * 32 + jj] + compat_logits[jj * 32 + ii]);
      csig[k] = 1.0f / (1.0f + expf(-l));
    }
  }
}

// ---------------------------------------------------------------------------
// bh[s][c] = b_sense_s . W_head_col_c  (exact fp32)
// ---------------------------------------------------------------------------
__global__ __launch_bounds__(256) void k_bh(
    const float* __restrict__ b_sense, const float* __restrict__ W_charge,
    const float* __restrict__ W_shell, const float* __restrict__ W_class,
    const float* __restrict__ W_mass, float* __restrict__ bh)
{
  const int c = blockIdx.x, s = blockIdx.y;
  const int tid = threadIdx.x;
  __shared__ float red[256];
  float p = 0.0f;
  for (int e = tid; e < 1024; e += 256) {
    float w;
    if (c == 0) w = W_charge[e];
    else if (c < 4) w = W_shell[e * 3 + (c - 1)];
    else if (c == 4) w = W_mass[e];
    else w = W_class[e * 32 + (c - 5)];
    p += b_sense[s * 1024 + e] * w;
  }
  red[tid] = p;
  __syncthreads();
  for (int st = 128; st > 0; st >>= 1) {
    if (tid < st) red[tid] += red[tid + st];
    __syncthreads();
  }
  if (tid == 0) bh[s * 128 + c] = red[0];
}

// ---------------------------------------------------------------------------
// Mt partial reduce: Mt[s][i] = sum_kc Mtp[s*8+kc][i]
// ---------------------------------------------------------------------------
__global__ __launch_bounds__(256) void k_reduce_mt(const float* __restrict__ Mtp,
                                                   float* __restrict__ Mt) {
  long o = (long)blockIdx.x * 256 + threadIdx.x;
  if (o >= 393216L) return;
  long s = o >> 17;
  long i = o & 131071;
  const float* p = Mtp + s * 8 * 131072 + i;
  float acc = 0.0f;
#pragma unroll
  for (int kc = 0; kc < 8; kc++) acc += p[(size_t)kc * 131072];
  Mt[o] = acc;
}

// ---------------------------------------------------------------------------
// Mt (fp32 [3][128][1024]) + W_sel -> Mthl[512][3072] = [hi | lo | hi]
// ---------------------------------------------------------------------------
__global__ __launch_bounds__(256) void k_split(const float* __restrict__ Mt,
                                               const float* __restrict__ W_sel,
                                               bf16* __restrict__ Mthl) {
  long id = (long)blockIdx.x * 256 + threadIdx.x;   // 512*3072
  if (id >= 1572864L) return;
  int n = (int)(id / 3072);
  int k = (int)(id - (long)n * 3072);
  int third = k >> 10;
  int j = k & 1023;
  float v;
  if (n < 384) {
    v = Mt[(size_t)n * 1024 + j];
  } else {
    int c2 = n - 384;
    v = (c2 < 3) ? W_sel[(size_t)j * 3 + c2] : 0.0f;
  }
  bf16 h = f2bf(v);
  Mthl[id] = (third == 1) ? f2bf(v - bf2f(h)) : h;
}

// ---------------------------------------------------------------------------
// xbar[b][d] = mean_n x[b][n][d]
// ---------------------------------------------------------------------------
__global__ __launch_bounds__(256) void k_xbar(const float* __restrict__ x, float* __restrict__ xbar) {
  const int d = blockIdx.x * 256 + threadIdx.x;
  const int b = blockIdx.y;
  const int n0 = blockIdx.z * 256;
  const float* xb = x + (size_t)b * 2048 * 1024 + (size_t)n0 * 1024 + d;
  float s = 0.0f;
  for (int n = 0; n < 256; n++) s += xb[(size_t)n * 1024];
  atomicAdd(&xbar[b * 1024 + d], s * (1.0f / 2048.0f));
}

// ---------------------------------------------------------------------------
// q[e][s] = sum_d W_ctx[e][d]*W_sel[1024+d][s]; q[1024][s] from b_ctx
// ---------------------------------------------------------------------------
__global__ __launch_bounds__(256) void k_q(const float* __restrict__ W_ctx,
                                           const float* __restrict__ b_ctx,
                                           const float* __restrict__ W_sel,
                                           float* __restrict__ q) {
  const int e = blockIdx.x;
  const int tid = threadIdx.x;
  const float* row = (e < 1024) ? (W_ctx + (size_t)e * 1024) : b_ctx;
  float p0 = 0.0f, p1 = 0.0f, p2 = 0.0f;
  for (int d = tid; d < 1024; d += 256) {
    float v = row[d];
    const float* ws = W_sel + (size_t)(1024 + d) * 3;
    p0 += v * ws[0]; p1 += v * ws[1]; p2 += v * ws[2];
  }
  __shared__ float red[3][256];
  red[0][tid] = p0; red[1][tid] = p1; red[2][tid] = p2;
  __syncthreads();
  for (int st = 128; st > 0; st >>= 1) {
    if (tid < st) {
      red[0][tid] += red[0][tid + st];
      red[1][tid] += red[1][tid + st];
      red[2][tid] += red[2][tid + st];
    }
    __syncthreads();
  }
  if (tid < 3) q[(size_t)e * 3 + tid] = red[tid][0];
}

// ---------------------------------------------------------------------------
__global__ __launch_bounds__(256) void k_ctxsel(const float* __restrict__ xbar,
                                                const float* __restrict__ q,
                                                float* __restrict__ ctx_sel) {
  const int b = blockIdx.x;
  const int tid = threadIdx.x;
  float p0 = 0.0f, p1 = 0.0f, p2 = 0.0f;
  for (int e = tid; e < 1024; e += 256) {
    float v = xbar[b * 1024 + e];
    p0 += v * q[e * 3 + 0]; p1 += v * q[e * 3 + 1]; p2 += v * q[e * 3 + 2];
  }
  __shared__ float red[3][256];
  red[0][tid] = p0; red[1][tid] = p1; red[2][tid] = p2;
  __syncthreads();
  for (int st = 128; st > 0; st >>= 1) {
    if (tid < st) {
      red[0][tid] += red[0][tid + st];
      red[1][tid] += red[1][tid + st];
      red[2][tid] += red[2][tid + st];
    }
    __syncthreads();
  }
  if (tid < 3) ctx_sel[b * 3 + tid] = red[tid][0] + q[1024 * 3 + tid];
}

// ---------------------------------------------------------------------------
// Per token: sense softmax weights -> sw[t][4]; head features -> feat[t][8]
// 4 tokens per 256-thread block (64-lane groups). H = 2 split-K planes.
// ---------------------------------------------------------------------------
__global__ __launch_bounds__(256) void k_heads(
    const float* __restrict__ H, const float* __restrict__ ctx_sel,
    const float* __restrict__ b_sel, const float* __restrict__ bh,
    const float* __restrict__ bhead,
    float* __restrict__ sw, float* __restrict__ feat)
{
  const int g = threadIdx.x >> 6;
  const int lane = threadIdx.x & 63;
  const int t = blockIdx.x * 4 + g;
  const int b = t >> 11;
  const float* Ht = H + (size_t)t * 512;
  const float* Ht2 = H + 4194304 + (size_t)t * 512;

  float s0 = Ht[384] + Ht2[384] + ctx_sel[b * 3 + 0] + b_sel[0];
  float s1 = Ht[385] + Ht2[385] + ctx_sel[b * 3 + 1] + b_sel[1];
  float s2 = Ht[386] + Ht2[386] + ctx_sel[b * 3 + 2] + b_sel[2];
  float mx = fmaxf(s0, fmaxf(s1, s2));
  float e0 = expf(s0 - mx), e1 = expf(s1 - mx), e2 = expf(s2 - mx);
  float inv = 1.0f / (e0 + e1 + e2);
  float w0 = e0 * inv, w1 = e1 * inv, w2 = e2 * inv;

  __shared__ float L[4][64];
  if (lane < 37) {
    float lg = bhead[lane];
    lg += w0 * (Ht[lane] + Ht2[lane] + bh[lane]);
    lg += w1 * (Ht[128 + lane] + Ht2[128 + lane] + bh[128 + lane]);
    lg += w2 * (Ht[256 + lane] + Ht2[256 + lane] + bh[256 + lane]);
    L[g][lane] = lg;
  }
  __syncthreads();
  if (lane == 0) {
    float charge = tanhf(L[g][0]);
    float h0 = L[g][1], h1 = L[g][2], h2 = L[g][3];
    float hm = fmaxf(h0, fmaxf(h1, h2));
    float x0 = expf(h0 - hm), x1 = expf(h1 - hm), x2 = expf(h2 - hm);
    float hinv = 1.0f / (x0 + x1 + x2);
    float mass = softplusf(L[g][4]) + 0.5f;
    int cls = 0;
    float best = L[g][5];
    for (int c = 1; c < 32; c++) {
      if (L[g][5 + c] > best) { best = L[g][5 + c]; cls = c; }
    }
    float* f = feat + (size_t)t * 8;
    f[0] = charge; f[1] = mass;
    f[2] = x0 * hinv; f[3] = x1 * hinv; f[4] = x2 * hinv;
    f[5] = (float)cls; f[6] = 0.0f; f[7] = 0.0f;
    float* sp_ = sw + (size_t)t * 4;
    sp_[0] = w0; sp_[1] = w1; sp_[2] = w2; sp_[3] = 0.0f;
  }
}

// ---------------------------------------------------------------------------
__global__ __launch_bounds__(256) void k_scores(
    const float* __restrict__ feat, const float* __restrict__ compat,
    const float* __restrict__ wchg, const float* __restrict__ wsh,
    const float* __restrict__ wdist, const float* __restrict__ wmass,
    const float* __restrict__ wval, const float* __restrict__ temp_p,
    bf16* __restrict__ P)
{
  const int i = blockIdx.x, b = blockIdx.y;
  const int tid = threadIdx.x;
  __shared__ float cs[1024];
  __shared__ float red[256];
  for (int k = tid; k < 1024; k += 256) cs[k] = compat[k];
  __syncthreads();

  const float a = softplusf(wchg[0]);
  const float bs = softplusf(wsh[0]);
  const float c = softplusf(wdist[0]);
  const float dm = softplusf(wmass[0]);
  const float ev = softplusf(wval[0]);
  const float itmp = 1.0f / softplusf(temp_p[0]);

  const float4* fi4 = (const float4*)(feat + ((size_t)b * 2048 + i) * 8);
  float4 fiA = fi4[0], fiB = fi4[1];
  const float ci = fiA.x, mi = fiA.y, si0 = fiA.z, si1 = fiA.w, si2 = fiB.x;
  int cli = (int)fiB.y; cli = cli < 0 ? 0 : (cli > 31 ? 31 : cli);

  float sc[8];
  float lmax = -3.0e38f;
#pragma unroll
  for (int jj = 0; jj < 8; jj++) {
    int j = tid + jj * 256;
    const float4* fj4 = (const float4*)(feat + ((size_t)b * 2048 + j) * 8);
    float4 fjA = fj4[0], fjB = fj4[1];
    int clj = (int)fjB.y; clj = clj < 0 ? 0 : (clj > 31 ? 31 : clj);
    float E = a * ci * fjA.x
            + bs * (fabsf(si0 - fjA.z) + fabsf(si1 - fjA.w) + fabsf(si2 - fjB.x))
            - c / (1.0f + 0.1f * fabsf((float)(i - j)))
            + dm * 0.1f * mi * fjA.y
            - ev;
    float s = (j <= i) ? (-E * itmp) * cs[cli * 32 + clj] : -3.0e38f;
    sc[jj] = s;
    lmax = fmaxf(lmax, s);
  }
  red[tid] = lmax;
  __syncthreads();
  for (int st = 128; st > 0; st >>= 1) {
    if (tid < st) red[tid] = fmaxf(red[tid], red[tid + st]);
    __syncthreads();
  }
  const float mrow = red[0];
  __syncthreads();

  float pv[8];
  float lsum = 0.0f;
#pragma unroll
  for (int jj = 0; jj < 8; jj++) {
    pv[jj] = (sc[jj] > -1.0e37f) ? expf(sc[jj] - mrow) : 0.0f;
    lsum += pv[jj];
  }
  red[tid] = lsum;
  __syncthreads();
  for (int st = 128; st > 0; st >>= 1) {
    if (tid < st) red[tid] += red[tid + st];
    __syncthreads();
  }
  const float inv = 1.0f / red[0];
  bf16* Pi = P + ((size_t)b * 2048 + i) * 2048;
#pragma unroll
  for (int jj = 0; jj < 8; jj++) Pi[tid + jj * 256] = f2bf(pv[jj] * inv);
}

// ---------------------------------------------------------------------------
extern "C" void kernel_launch(void* const* d_in, const int* in_sizes, int n_in,
                              void* d_out, int out_size, void* d_ws, size_t ws_size,
                              hipStream_t stream) {
  (void)in_sizes; (void)n_in; (void)out_size; (void)ws_size;
  const float* x        = (const float*)d_in[0];
  const float* W_sense  = (const float*)d_in[1];
  const float* b_sense  = (const float*)d_in[2];
  const float* W_ctx    = (const float*)d_in[3];
  const float* b_ctx    = (const float*)d_in[4];
  const float* W_sel    = (const float*)d_in[5];
  const float* b_sel    = (const float*)d_in[6];
  const float* W_charge = (const float*)d_in[7];
  const float* b_charge = (const float*)d_in[8];
  const float* W_shell  = (const float*)d_in[9];
  const float* b_shell  = (const float*)d_in[10];
  const float* W_class  = (const float*)d_in[11];
  const float* b_class  = (const float*)d_in[12];
  const float* W_mass   = (const float*)d_in[13];
  const float* b_mass   = (const float*)d_in[14];
  const float* compat_logits = (const float*)d_in[17];
  const float* w_charge = (const float*)d_in[18];
  const float* w_shell  = (const float*)d_in[19];
  const float* w_distance = (const float*)d_in[20];
  const float* w_mass   = (const float*)d_in[21];
  const float* w_valence = (const float*)d_in[22];
  const float* temperature = (const float*)d_in[23];
  const float* W_v      = (const float*)d_in[24];
  const float* b_v      = (const float*)d_in[25];
  const float* W_out    = (const float*)d_in[26];
  const float* b_out    = (const float*)d_in[27];

  char* w = (char*)d_ws;
  auto alloc = [&](size_t bytes) {
    char* p = w;
    w += (bytes + 255) & ~(size_t)255;
    return p;
  };
  bf16* xhhl  = (bf16*)alloc(8192ULL * 3072 * 2);
  char* R1    = alloc(48ULL * 1024 * 1024);
  bf16* Wsn3  = (bf16*)R1;
  float* Hh   = (float*)R1;
  float* Mtp  = (float*)(R1 + 20ULL * 1024 * 1024);      // [24][131072] fp32
  bf16* Mthl  = (bf16*)(R1 + 40ULL * 1024 * 1024);       // [512][3072] bf16
  float* Mt   = (float*)(R1 + 44ULL * 1024 * 1024);      // [3][128][1024] fp32
  bf16* y     = (bf16*)R1;                               // [8192][1024] bf16
  bf16* Wts2  = (bf16*)alloc(3072ULL * 1024 * 2);        // Bt2 [1024][3072]
  bf16* Wt_v  = (bf16*)alloc(1024ULL * 1024 * 2);
  bf16* Wt_out = (bf16*)alloc(1024ULL * 1024 * 2);
  bf16* Whhl3 = (bf16*)alloc(128ULL * 3072 * 2);
  float* bh   = (float*)alloc(3ULL * 128 * 4);
  float* bhead = (float*)alloc(256);
  float* csig = (float*)alloc(4096);
  float* xbar = (float*)alloc(4ULL * 1024 * 4);
  float* qbuf = (float*)alloc(1025ULL * 3 * 4);
  float* ctx_sel = (float*)alloc(256);
  float* feat = (float*)alloc(8192ULL * 8 * 4);
  float* sw   = (float*)alloc(8192ULL * 4 * 4);
  // aliases inside xhhl (48 MB flat); Vt/O written only after gemm_y is done
  bf16* Vt = xhhl + 8388608;          // 16 MB
  bf16* O  = xhhl + 16777216;         // 16 MB
  bf16* P  = (bf16*)d_out;            // 32 MiB; consumed before final GEMM

  // ---- input conversions ----
  k_split_x3<<<32768, 256, 0, stream>>>(x, xhhl);
  k_split_ws3<<<12288, 256, 0, stream>>>(W_sense, Wsn3);
  k_trans_sense<<<dim3(32, 32, 3), 256, 0, stream>>>(W_sense, Wts2);
  k_trans_hl<<<dim3(32, 32), 256, 0, stream>>>(W_v, Wt_v, 1024, 1024);
  k_trans_hl<<<dim3(32, 32), 256, 0, stream>>>(W_out, Wt_out, 1024, 1024);
  k_pack<<<128, 256, 0, stream>>>(W_charge, W_shell, W_class, W_mass,
                                  b_charge, b_shell, b_class, b_mass,
                                  compat_logits, Whhl3, bhead, csig);

  // ---- ctx path ----
  hipMemsetAsync(xbar, 0, 4096 * 4, stream);
  k_xbar<<<dim3(4, 4, 8), 256, 0, stream>>>(x, xbar);
  k_q<<<1025, 256, 0, stream>>>(W_ctx, b_ctx, W_sel, qbuf);
  k_ctxsel<<<4, 256, 0, stream>>>(xbar, qbuf, ctx_sel);

  // ---- Mt fold: 8-way K-split (chunk=384) -> 192 blocks, then reduce ----
  gemm_bt<1, 0, 0, 0, 8><<<dim3(8, 1, 24), 512, 0, stream>>>(
      Whhl3, Wsn3, nullptr, Mtp, 128, 1024, 384, 3072, 3072, 1024,
      0, 3145728L, 131072L);
  k_reduce_mt<<<1536, 256, 0, stream>>>(Mtp, Mt);
  k_split<<<6144, 256, 0, stream>>>(Mt, W_sel, Mthl);

  // ---- H = x @ [Mt | Wsel]^T, 2-way K-split (chunk=1536) -> 512 blocks ----
  gemm_bt<1, 0, 0, 1, 2><<<dim3(256, 1, 2), 512, 0, stream>>>(
      xhhl, Mthl, nullptr, Hh, 8192, 512, 1536, 3072, 3072, 512,
      0, 0, 4194304L);

  // ---- bh (exact fp32) + per-token heads (sums the 2 H planes) ----
  k_bh<<<dim3(37, 3), 256, 0, stream>>>(b_sense, W_charge, W_shell, W_class, W_mass, bh);
  k_heads<<<2048, 256, 0, stream>>>(Hh, ctx_sel, b_sel, bh, bhead, sw, feat);

  // ---- y = sum_s sw_s*(x @ W_sense_s) + sw-wtd bias (boundary-scaled) ----
  gemm_y<<<512, 512, 0, stream>>>(xhhl, Wts2, b_sense, sw, y);

  // ---- V^T (batched): Vt[b][d][n], LDS-transposed coalesced epilogue ----
  gemm_bt<2, 0, 0, 1><<<512, 512, 0, stream>>>(
      y, Wt_v, b_v, Vt, 8192, 1024, 1024, 1024, 1024, 0, 0, 0, 0);

  // ---- P = causal softmax of pair scores (in d_out) ----
  k_scores<<<dim3(2048, 4), 256, 0, stream>>>(feat, csig, w_charge, w_shell,
                                              w_distance, w_mass, w_valence, temperature, P);

  // ---- O = P @ V (causal k-limit, heavy-first), per batch ----
  gemm_bt<0, 1, 0, 0><<<dim3(8, 16, 4), 512, 0, stream>>>(
      P, Vt, nullptr, O, 2048, 1024, 2048, 2048, 2048, 1024,
      2048L * 2048, 1024L * 2048, 2048L * 1024);

  // ---- out = O @ W_out + b_out (fp32, overwrites P) ----
  gemm_bt<1, 0, 0, 1><<<512, 512, 0, stream>>>(
      O, Wt_out, b_out, (float*)d_out, 8192, 1024, 1024, 1024, 1024, 1024, 0, 0, 0);
}

// Round 18
// 484.728 us; speedup vs baseline: 1.1480x; 1.0047x over previous
//
#include <hip/hip_runtime.h>
#include <hip/hip_bf16.h>
#include <cmath>

typedef __hip_bfloat16 bf16;
typedef __attribute__((ext_vector_type(4))) float floatx4;
typedef __attribute__((ext_vector_type(8))) short short8;
typedef __attribute__((ext_vector_type(8))) unsigned short ushort8;

__device__ __forceinline__ float bf2f(bf16 v) { return __bfloat162float(v); }
__device__ __forceinline__ bf16 f2bf(float v) { return __float2bfloat16(v); }
__device__ __forceinline__ float bfu2f(unsigned short u) { return __uint_as_float(((unsigned)u) << 16); }
__device__ __forceinline__ unsigned short f2bfu(float v) {
  bf16 h = __float2bfloat16(v);
  return __builtin_bit_cast(unsigned short, h);
}
__device__ __forceinline__ float softplusf(float x) {
  return x > 20.0f ? x : log1pf(expf(x));
}

__device__ __forceinline__ void async16(const void* g, void* l) {
  __builtin_amdgcn_global_load_lds(
      (const __attribute__((address_space(1))) unsigned int*)g,
      (__attribute__((address_space(3))) unsigned int*)l, 16, 0, 0);
}

// ---------------------------------------------------------------------------
// Generic bf16 GEMM: C[m][n] = sum_k A[m][k] * Bt[n][k]  (+ fp32 bias[n])
// 512 threads / 8 waves per block over a 128x128 tile (wave = 32x64 out:
// 2x4 frags of 16x16x32).
// QUAD-buffered BK=32, prefetch distance 3 (round-16 analysis: step ~307cyc,
// distance-2 window 614cyc < HBM latency ~900cyc (m126) -> every step stalled
// on vmcnt; distance-3 window ~920cyc covers it). buf = t&3, stage (t+3)&3
// (WAR-safe: that buffer's reads retired before the t-1 barrier). Steady wait
// vmcnt(4) = t+1's 2 loads done, 2 tiles (4 loads) in flight; tail 4->2->0.
// 64KB LDS -> 2 blocks/CU = 16 waves/CU (launch_bounds(512,4)).
// LDS swizzle (both-sides involution): physical 16B chunk c of row r holds
// logical chunk c ^ ((r>>1)&3); staged via pre-swizzled global source col.
// Read side: gph = (fm>>1)&3 == (R>>1)&3 because wr*32, wc*64, i*16 = 0 mod 4.
// MODE 0: bf16 out row-major (ldc).   MODE 1: fp32 out (ldc), ACCUM adds.
// MODE 2: bf16 out transposed-batched Vt[(m>>11)*1024+n][m&2047] via
//         LDS-transposed coalesced epilogue (round-16 measured: -16us total).
// CAUSAL: k limited to (m_tile+1)*128; m-tiles issued heavy-first.
// SWZ: flat grid.x = mtiles*ntiles; XCD-banded decode (bid&7 -> m band).
// KSPLIT>1: z = zz*KSPLIT + kc; K is the CHUNK length, kstart = kc*K.
// All K chunks must be multiples of 32.
// ---------------------------------------------------------------------------
template<int MODE, int CAUSAL, int ACCUM, int SWZ, int KSPLIT = 1>
__global__ __launch_bounds__(512, 4) void gemm_bt(
    const bf16* __restrict__ A, const bf16* __restrict__ Bt,
    const float* __restrict__ bias, void* __restrict__ Cptr,
    int M, int N, int K, int lda, int ldb, int ldc,
    long aoffz, long boffz, long coffz)
{
  __shared__ __align__(16) bf16 smem[8][128 * 32];   // As=smem[0..3], Bs=smem[4..7]
  bf16 (*As)[128 * 32] = &smem[0];
  bf16 (*Bs)[128 * 32] = &smem[4];

  const int tid = threadIdx.x;
  const int lane = tid & 63;
  const int wave = tid >> 6;            // 0..7
  const int wr = wave >> 1, wc = wave & 1;
  const long z = blockIdx.z;
  int kstart = 0;
  long zz = z;
  if (KSPLIT > 1) {
    kstart = (int)(z % KSPLIT) * K;
    zz = z / KSPLIT;
  }
  A += zz * aoffz;
  Bt += zz * boffz;

  int bx, by;
  if (SWZ) {
    const int mtiles = M >> 7;
    const int per = mtiles >> 3;          // m-tiles per XCD band
    const int bid = (int)blockIdx.x;
    const int xcd = bid & 7;
    const int slot = bid >> 3;
    by = xcd * per + (slot % per);
    bx = slot / per;
  } else {
    bx = blockIdx.x;
    by = blockIdx.y;
    if (CAUSAL) by = (int)gridDim.y - 1 - by;   // heavy tiles first
  }
  const int m0 = by * 128, n0 = bx * 128;
  int kend = kstart + K;
  if (CAUSAL) {
    int klim = (by + 1) * 128;
    if (klim < kend) kend = klim;
  }

  // Staging: 512 chunks of 16B per 128x32 tile; 1 chunk/thread/matrix.
  // chunk tid -> row srow = tid>>2, slot sc = tid&3; src logical chunk
  // sc ^ ((srow>>1)&3).
  const int srow = tid >> 2, sc = tid & 3;
  const int scol = (sc ^ ((srow >> 1) & 3)) * 8;
  const size_t a0 = (size_t)(m0 + srow) * lda + scol;
  const size_t b0 = (size_t)(n0 + srow) * ldb + scol;

  floatx4 acc[2][4] = {};
  const int fm = lane & 15, fq = lane >> 4;
  const int gph = (fm >> 1) & 3;
  const int nt = (kend - kstart) >> 5;

  auto stage = [&](int buf, int t) {
    const int k0 = kstart + t * 32;
    async16(&A[a0 + k0], &As[buf][tid * 8]);
    async16(&Bt[b0 + k0], &Bs[buf][tid * 8]);
  };

  stage(0, 0);
  if (nt > 1) stage(1, 1);
  if (nt > 2) stage(2, 2);
  if (nt > 2)      asm volatile("s_waitcnt vmcnt(4)" ::: "memory");
  else if (nt > 1) asm volatile("s_waitcnt vmcnt(2)" ::: "memory");
  else             asm volatile("s_waitcnt vmcnt(0)" ::: "memory");
  asm volatile("s_barrier" ::: "memory");

  for (int t = 0; t < nt; t++) {
    const int bufc = t & 3;
    if (t + 3 < nt) stage((t + 3) & 3, t + 3);
    short8 af[2], bfr[4];
#pragma unroll
    for (int i = 0; i < 2; i++) {
      int R = wr * 32 + i * 16 + fm;
      af[i] = *(const short8*)&As[bufc][R * 32 + ((fq ^ gph) << 3)];
    }
#pragma unroll
    for (int j = 0; j < 4; j++) {
      int R = wc * 64 + j * 16 + fm;
      bfr[j] = *(const short8*)&Bs[bufc][R * 32 + ((fq ^ gph) << 3)];
    }
#pragma unroll
    for (int i = 0; i < 2; i++)
#pragma unroll
      for (int j = 0; j < 4; j++)
        acc[i][j] = __builtin_amdgcn_mfma_f32_16x16x32_bf16(af[i], bfr[j], acc[i][j], 0, 0, 0);
    if (t + 3 < nt)      asm volatile("s_waitcnt vmcnt(4)" ::: "memory");
    else if (t + 2 < nt) asm volatile("s_waitcnt vmcnt(2)" ::: "memory");
    else                 asm volatile("s_waitcnt vmcnt(0)" ::: "memory");
    asm volatile("s_barrier" ::: "memory");
  }

  const int rm0 = (lane >> 4) * 4, cn = lane & 15;
  if constexpr (MODE == 2) {
    // LDS-transposed epilogue: staging LDS is dead past the final barrier.
    bf16* T = &smem[0][0];                 // [128 nn][stride 132] bf16, 33.8KB
#pragma unroll
    for (int i = 0; i < 2; i++)
#pragma unroll
      for (int j = 0; j < 4; j++) {
        int nn_l = wc * 64 + j * 16 + cn;
        float bv = bias ? bias[n0 + nn_l] : 0.0f;
#pragma unroll
        for (int r = 0; r < 4; r++) {
          int mm_l = wr * 32 + i * 16 + rm0 + r;
          T[nn_l * 132 + mm_l] = f2bf(acc[i][j][r] + bv);
        }
      }
    __syncthreads();
    const int bb = m0 >> 11, nb = m0 & 2047;
#pragma unroll
    for (int c4 = 0; c4 < 4; c4++) {
      int c = tid + c4 * 512;              // 2048 chunks of 8 bf16
      int row = c >> 4, col = (c & 15) << 3;
      ushort8 v8;
#pragma unroll
      for (int e = 0; e < 8; e++)
        v8[e] = __builtin_bit_cast(unsigned short, T[row * 132 + col + e]);
      *(ushort8*)&((bf16*)Cptr)[((size_t)(bb * 1024 + n0 + row)) * 2048 + nb + col] = v8;
    }
  } else {
#pragma unroll
    for (int i = 0; i < 2; i++) {
#pragma unroll
      for (int j = 0; j < 4; j++) {
        int nn = n0 + wc * 64 + j * 16 + cn;
        float bv = bias ? bias[nn] : 0.0f;
#pragma unroll
        for (int r = 0; r < 4; r++) {
          int mm = m0 + wr * 32 + i * 16 + rm0 + r;
          float v = acc[i][j][r] + bv;
          if (MODE == 0) {
            ((bf16*)Cptr)[z * coffz + (long)mm * ldc + nn] = f2bf(v);
          } else {
            long idx = z * coffz + (long)mm * ldc + nn;
            float* Cf = (float*)Cptr;
            if (ACCUM) v += Cf[idx];
            Cf[idx] = v;
          }
        }
      }
    }
  }
}

// ---------------------------------------------------------------------------
// Fused y GEMM: y[t][d] = sum_s sw_s[t] * (x[t] @ W_sense_s)[d] + sw-wtd bias
// A = xhhl hi third (bf16 x, lda=3072); no A' materialization.
// K' = 3072 = 3 senses x 1024; step t covers sense s = t>>5, x-cols
// ((t*32) & 1023).
// Sense scaling at ACCUMULATOR BOUNDARIES: plain MFMA into per-sense acc;
// at t = 31/63/95 fold accT += sw_s[row]*acc. [round-14 measured: 79.8us]
// QUAD-buffer prefetch distance 3 (same rationale as gemm_bt).
// Grid 512 = 64 mtiles x 8 ntiles, XCD-banded. Bt2[d][s*1024+k] per-sense.
// ---------------------------------------------------------------------------
__global__ __launch_bounds__(512, 4) void gemm_y(
    const bf16* __restrict__ A, const bf16* __restrict__ Bt,
    const float* __restrict__ bsense, const float* __restrict__ sw,
    bf16* __restrict__ y)
{
  __shared__ __align__(16) bf16 As[4][128 * 32];
  __shared__ __align__(16) bf16 Bs[4][128 * 32];

  const int tid = threadIdx.x;
  const int lane = tid & 63;
  const int wave = tid >> 6;
  const int wr = wave >> 1, wc = wave & 1;

  // mtiles=64, ntiles=8, XCD-banded
  const int bid = (int)blockIdx.x;
  const int xcd = bid & 7;
  const int slot = bid >> 3;
  const int by = xcd * 8 + (slot & 7);
  const int bx = slot >> 3;
  const int m0 = by * 128, n0 = bx * 128;

  const int srow = tid >> 2, sc = tid & 3;
  const int scol = (sc ^ ((srow >> 1) & 3)) * 8;
  const size_t a0 = (size_t)(m0 + srow) * 3072 + scol;   // x hi third
  const size_t b0 = (size_t)(n0 + srow) * 3072 + scol;

  floatx4 acc[2][4] = {};    // current-sense partial
  floatx4 accT[2][4] = {};   // weighted total
  const int fm = lane & 15, fq = lane >> 4;
  const int gph = (fm >> 1) & 3;
  const int rm0 = (lane >> 4) * 4;

  // preload sense weights for this thread's 8 C-fragment rows
  float sv0[2][4], sv1[2][4], sv2[2][4];
#pragma unroll
  for (int i = 0; i < 2; i++)
#pragma unroll
    for (int r = 0; r < 4; r++) {
      const float* sm = sw + (size_t)(m0 + wr * 32 + i * 16 + rm0 + r) * 4;
      float4 v4 = *(const float4*)sm;
      sv0[i][r] = v4.x; sv1[i][r] = v4.y; sv2[i][r] = v4.z;
    }

  auto stage = [&](int buf, int t) {
    const int k0a = (t * 32) & 1023;        // x repeats per sense
    const int k0b = t * 32;                  // B spans full 3072
    async16(&A[a0 + k0a], &As[buf][tid * 8]);
    async16(&Bt[b0 + k0b], &Bs[buf][tid * 8]);
  };

  stage(0, 0);
  stage(1, 1);
  stage(2, 2);
  asm volatile("s_waitcnt vmcnt(4)" ::: "memory");
  asm volatile("s_barrier" ::: "memory");

  for (int t = 0; t < 96; t++) {
    const int bufc = t & 3;
    if (t + 3 < 96) stage((t + 3) & 3, t + 3);
    short8 af[2], bfr[4];
#pragma unroll
    for (int i = 0; i < 2; i++) {
      int R = wr * 32 + i * 16 + fm;
      af[i] = *(const short8*)&As[bufc][R * 32 + ((fq ^ gph) << 3)];
    }
#pragma unroll
    for (int j = 0; j < 4; j++) {
      int R = wc * 64 + j * 16 + fm;
      bfr[j] = *(const short8*)&Bs[bufc][R * 32 + ((fq ^ gph) << 3)];
    }
#pragma unroll
    for (int i = 0; i < 2; i++)
#pragma unroll
      for (int j = 0; j < 4; j++)
        acc[i][j] = __builtin_amdgcn_mfma_f32_16x16x32_bf16(af[i], bfr[j], acc[i][j], 0, 0, 0);
    if ((t & 31) == 31) {
      // sense boundary: fold weighted partial into total (fp32), reset acc
      const int s = t >> 5;
#pragma unroll
      for (int i = 0; i < 2; i++)
#pragma unroll
        for (int r = 0; r < 4; r++) {
          float scl = (s == 0) ? sv0[i][r] : (s == 1) ? sv1[i][r] : sv2[i][r];
#pragma unroll
          for (int j = 0; j < 4; j++) {
            accT[i][j][r] += scl * acc[i][j][r];
            acc[i][j][r] = 0.0f;
          }
        }
    }
    if (t + 3 < 96)      asm volatile("s_waitcnt vmcnt(4)" ::: "memory");
    else if (t + 2 < 96) asm volatile("s_waitcnt vmcnt(2)" ::: "memory");
    else                 asm volatile("s_waitcnt vmcnt(0)" ::: "memory");
    asm volatile("s_barrier" ::: "memory");
  }

  const int cn = lane & 15;
#pragma unroll
  for (int j = 0; j < 4; j++) {
    int nn = n0 + wc * 64 + j * 16 + cn;
    float bb0 = bsense[nn], bb1 = bsense[1024 + nn], bb2 = bsense[2048 + nn];
#pragma unroll
    for (int i = 0; i < 2; i++) {
#pragma unroll
      for (int r = 0; r < 4; r++) {
        int mm = m0 + wr * 32 + i * 16 + rm0 + r;
        float v = accT[i][j][r] + sv0[i][r] * bb0 + sv1[i][r] * bb1 + sv2[i][r] * bb2;
        y[(size_t)mm * 1024 + nn] = f2bf(v);
      }
    }
  }
}

// ---------------------------------------------------------------------------
// x (fp32, 8192x1024) -> xhhl[t][3072] = [hi | hi | lo]
// ---------------------------------------------------------------------------
__global__ __launch_bounds__(256) void k_split_x3(const float* __restrict__ x,
                                                  bf16* __restrict__ xhhl) {
  long id = (long)blockIdx.x * 256 + threadIdx.x;
  if (id >= 8388608L) return;
  long t = id >> 10;
  int d = (int)(id & 1023);
  float v = x[id];
  bf16 h = f2bf(v);
  bf16 l = f2bf(v - bf2f(h));
  bf16* row = xhhl + t * 3072;
  row[d] = h;
  row[1024 + d] = h;
  row[2048 + d] = l;
}

// ---------------------------------------------------------------------------
// W_sense (fp32, 1024x3072) -> Wsn3[s][d][3072] = [hi | lo | hi]
// ---------------------------------------------------------------------------
__global__ __launch_bounds__(256) void k_split_ws3(const float* __restrict__ Ws,
                                                   bf16* __restrict__ Wsn3) {
  long id = (long)blockIdx.x * 256 + threadIdx.x;
  if (id >= 3145728L) return;
  int row10 = (int)(id >> 10);   // = d*3 + s
  int d = row10 / 3;
  int s = row10 - d * 3;
  int dp = (int)(id & 1023);
  float v = Ws[id];
  bf16 h = f2bf(v);
  bf16 l = f2bf(v - bf2f(h));
  bf16* row = Wsn3 + ((size_t)(s * 1024 + d)) * 3072;
  row[dp] = h;
  row[1024 + dp] = l;
  row[2048 + dp] = h;
}

// ---------------------------------------------------------------------------
// Transpose fp32 src[R][C] -> bf16 dh[C][R]
// ---------------------------------------------------------------------------
__global__ __launch_bounds__(256) void k_trans_hl(const float* __restrict__ src,
                                                  bf16* __restrict__ dh,
                                                  int R, int C) {
  __shared__ float tile[32][33];
  int c0 = blockIdx.x * 32, r0 = blockIdx.y * 32;
  int tx = threadIdx.x & 31, ty = threadIdx.x >> 5;
  for (int rr = ty; rr < 32; rr += 8)
    tile[rr][tx] = src[(size_t)(r0 + rr) * C + c0 + tx];
  __syncthreads();
  for (int rr = ty; rr < 32; rr += 8)
    dh[(size_t)(c0 + rr) * R + r0 + tx] = f2bf(tile[tx][rr]);
}

// ---------------------------------------------------------------------------
// Per-sense transpose: Bt2[d][s*1024+k] = W_sense[k][s*1024+d]  (bf16 hi)
// grid (32, 32, 3)
// ---------------------------------------------------------------------------
__global__ __launch_bounds__(256) void k_trans_sense(const float* __restrict__ Ws,
                                                     bf16* __restrict__ Bt2) {
  __shared__ float tile[32][33];
  int c0 = blockIdx.x * 32, r0 = blockIdx.y * 32, s = blockIdx.z;
  int tx = threadIdx.x & 31, ty = threadIdx.x >> 5;
  for (int rr = ty; rr < 32; rr += 8)
    tile[rr][tx] = Ws[(size_t)(r0 + rr) * 3072 + s * 1024 + c0 + tx];
  __syncthreads();
  for (int rr = ty; rr < 32; rr += 8)
    Bt2[(size_t)(c0 + rr) * 3072 + s * 1024 + r0 + tx] = f2bf(tile[tx][rr]);
}

// ---------------------------------------------------------------------------
// Pack head weights -> Whhl3[c][3072] = [hi | hi | lo]; bhead[37]; csig[1024]
// ---------------------------------------------------------------------------
__global__ __launch_bounds__(256) void k_pack(
    const float* __restrict__ W_charge, const float* __restrict__ W_shell,
    const float* __restrict__ W_class, const float* __restrict__ W_mass,
    const float* __restrict__ b_charge, const float* __restrict__ b_shell,
    const float* __restrict__ b_class, const float* __restrict__ b_mass,
    const float* __restrict__ compat_logits,
    bf16* __restrict__ Whhl3, float* __restrict__ bhead, float* __restrict__ csig)
{
  int c = blockIdx.x;
  int tid = threadIdx.x;
  for (int e = tid; e < 1024; e += 256) {
    float v;
    if (c == 0) v = W_charge[e];
    else if (c < 4) v = W_shell[e * 3 + (c - 1)];
    else if (c == 4) v = W_mass[e];
    else if (c < 37) v = W_class[e * 32 + (c - 5)];
    else v = 0.0f;
    bf16 h = f2bf(v);
    bf16 l = f2bf(v - bf2f(h));
    bf16* row = Whhl3 + (size_t)c * 3072;
    row[e] = h;
    row[1024 + e] = h;
    row[2048 + e] = l;
  }
  if (c == 0 && tid < 37) {
    float v;
    if (tid == 0) v = b_charge[0];
    else if (tid < 4) v = b_shell[tid - 1];
    else if (tid == 4) v = b_mass[0];
    else v = b_class[tid - 5];
    bhead[tid] = v;
  }
  if (c == 1) {
    for (int k = tid; k < 1024; k += 256) {
      int ii = k >> 5, jj = k & 31;
      float l = 0.5f * (compat_logits[ii * 32 + jj] + compat_logits[jj * 32 + ii]);
      csig[k] = 1.0f / (1.0f + expf(-l));
    }
  }
}

// ---------------------------------------------------------------------------
// bh[s][c] = b_sense_s . W_head_col_c  (exact fp32)
// ---------------------------------------------------------------------------
__global__ __launch_bounds__(256) void k_bh(
    const float* __restrict__ b_sense, const float* __restrict__ W_charge,
    const float* __restrict__ W_shell, const float* __restrict__ W_class,
    const float* __restrict__ W_mass, float* __restrict__ bh)
{
  const int c = blockIdx.x, s = blockIdx.y;
  const int tid = threadIdx.x;
  __shared__ float red[256];
  float p = 0.0f;
  for (int e = tid; e < 1024; e += 256) {
    float w;
    if (c == 0) w = W_charge[e];
    else if (c < 4) w = W_shell[e * 3 + (c - 1)];
    else if (c == 4) w = W_mass[e];
    else w = W_class[e * 32 + (c - 5)];
    p += b_sense[s * 1024 + e] * w;
  }
  red[tid] = p;
  __syncthreads();
  for (int st = 128; st > 0; st >>= 1) {
    if (tid < st) red[tid] += red[tid + st];
    __syncthreads();
  }
  if (tid == 0) bh[s * 128 + c] = red[0];
}

// ---------------------------------------------------------------------------
// Mt partial reduce: Mt[s][i] = sum_kc Mtp[s*8+kc][i]
// ---------------------------------------------------------------------------
__global__ __launch_bounds__(256) void k_reduce_mt(const float* __restrict__ Mtp,
                                                   float* __restrict__ Mt) {
  long o = (long)blockIdx.x * 256 + threadIdx.x;
  if (o >= 393216L) return;
  long s = o >> 17;
  long i = o & 131071;
  const float* p = Mtp + s * 8 * 131072 + i;
  float acc = 0.0f;
#pragma unroll
  for (int kc = 0; kc < 8; kc++) acc += p[(size_t)kc * 131072];
  Mt[o] = acc;
}

// ---------------------------------------------------------------------------
// Mt (fp32 [3][128][1024]) + W_sel -> Mthl[512][3072] = [hi | lo | hi]
// ---------------------------------------------------------------------------
__global__ __launch_bounds__(256) void k_split(const float* __restrict__ Mt,
                                               const float* __restrict__ W_sel,
                                               bf16* __restrict__ Mthl) {
  long id = (long)blockIdx.x * 256 + threadIdx.x;   // 512*3072
  if (id >= 1572864L) return;
  int n = (int)(id / 3072);
  int k = (int)(id - (long)n * 3072);
  int third = k >> 10;
  int j = k & 1023;
  float v;
  if (n < 384) {
    v = Mt[(size_t)n * 1024 + j];
  } else {
    int c2 = n - 384;
    v = (c2 < 3) ? W_sel[(size_t)j * 3 + c2] : 0.0f;
  }
  bf16 h = f2bf(v);
  Mthl[id] = (third == 1) ? f2bf(v - bf2f(h)) : h;
}

// ---------------------------------------------------------------------------
// xbar[b][d] = mean_n x[b][n][d]
// ---------------------------------------------------------------------------
__global__ __launch_bounds__(256) void k_xbar(const float* __restrict__ x, float* __restrict__ xbar) {
  const int d = blockIdx.x * 256 + threadIdx.x;
  const int b = blockIdx.y;
  const int n0 = blockIdx.z * 256;
  const float* xb = x + (size_t)b * 2048 * 1024 + (size_t)n0 * 1024 + d;
  float s = 0.0f;
  for (int n = 0; n < 256; n++) s += xb[(size_t)n * 1024];
  atomicAdd(&xbar[b * 1024 + d], s * (1.0f / 2048.0f));
}

// ---------------------------------------------------------------------------
// q[e][s] = sum_d W_ctx[e][d]*W_sel[1024+d][s]; q[1024][s] from b_ctx
// ---------------------------------------------------------------------------
__global__ __launch_bounds__(256) void k_q(const float* __restrict__ W_ctx,
                                           const float* __restrict__ b_ctx,
                                           const float* __restrict__ W_sel,
                                           float* __restrict__ q) {
  const int e = blockIdx.x;
  const int tid = threadIdx.x;
  const float* row = (e < 1024) ? (W_ctx + (size_t)e * 1024) : b_ctx;
  float p0 = 0.0f, p1 = 0.0f, p2 = 0.0f;
  for (int d = tid; d < 1024; d += 256) {
    float v = row[d];
    const float* ws = W_sel + (size_t)(1024 + d) * 3;
    p0 += v * ws[0]; p1 += v * ws[1]; p2 += v * ws[2];
  }
  __shared__ float red[3][256];
  red[0][tid] = p0; red[1][tid] = p1; red[2][tid] = p2;
  __syncthreads();
  for (int st = 128; st > 0; st >>= 1) {
    if (tid < st) {
      red[0][tid] += red[0][tid + st];
      red[1][tid] += red[1][tid + st];
      red[2][tid] += red[2][tid + st];
    }
    __syncthreads();
  }
  if (tid < 3) q[(size_t)e * 3 + tid] = red[tid][0];
}

// ---------------------------------------------------------------------------
__global__ __launch_bounds__(256) void k_ctxsel(const float* __restrict__ xbar,
                                                const float* __restrict__ q,
                                                float* __restrict__ ctx_sel) {
  const int b = blockIdx.x;
  const int tid = threadIdx.x;
  float p0 = 0.0f, p1 = 0.0f, p2 = 0.0f;
  for (int e = tid; e < 1024; e += 256) {
    float v = xbar[b * 1024 + e];
    p0 += v * q[e * 3 + 0]; p1 += v * q[e * 3 + 1]; p2 += v * q[e * 3 + 2];
  }
  __shared__ float red[3][256];
  red[0][tid] = p0; red[1][tid] = p1; red[2][tid] = p2;
  __syncthreads();
  for (int st = 128; st > 0; st >>= 1) {
    if (tid < st) {
      red[0][tid] += red[0][tid + st];
      red[1][tid] += red[1][tid + st];
      red[2][tid] += red[2][tid + st];
    }
    __syncthreads();
  }
  if (tid < 3) ctx_sel[b * 3 + tid] = red[tid][0] + q[1024 * 3 + tid];
}

// ---------------------------------------------------------------------------
// Per token: sense softmax weights -> sw[t][4]; head features -> feat[t][8]
// 4 tokens per 256-thread block (64-lane groups). H = 2 split-K planes.
// ---------------------------------------------------------------------------
__global__ __launch_bounds__(256) void k_heads(
    const float* __restrict__ H, const float* __restrict__ ctx_sel,
    const float* __restrict__ b_sel, const float* __restrict__ bh,
    const float* __restrict__ bhead,
    float* __restrict__ sw, float* __restrict__ feat)
{
  const int g = threadIdx.x >> 6;
  const int lane = threadIdx.x & 63;
  const int t = blockIdx.x * 4 + g;
  const int b = t >> 11;
  const float* Ht = H + (size_t)t * 512;
  const float* Ht2 = H + 4194304 + (size_t)t * 512;

  float s0 = Ht[384] + Ht2[384] + ctx_sel[b * 3 + 0] + b_sel[0];
  float s1 = Ht[385] + Ht2[385] + ctx_sel[b * 3 + 1] + b_sel[1];
  float s2 = Ht[386] + Ht2[386] + ctx_sel[b * 3 + 2] + b_sel[2];
  float mx = fmaxf(s0, fmaxf(s1, s2));
  float e0 = expf(s0 - mx), e1 = expf(s1 - mx), e2 = expf(s2 - mx);
  float inv = 1.0f / (e0 + e1 + e2);
  float w0 = e0 * inv, w1 = e1 * inv, w2 = e2 * inv;

  __shared__ float L[4][64];
  if (lane < 37) {
    float lg = bhead[lane];
    lg += w0 * (Ht[lane] + Ht2[lane] + bh[lane]);
    lg += w1 * (Ht[128 + lane] + Ht2[128 + lane] + bh[128 + lane]);
    lg += w2 * (Ht[256 + lane] + Ht2[256 + lane] + bh[256 + lane]);
    L[g][lane] = lg;
  }
  __syncthreads();
  if (lane == 0) {
    float charge = tanhf(L[g][0]);
    float h0 = L[g][1], h1 = L[g][2], h2 = L[g][3];
    float hm = fmaxf(h0, fmaxf(h1, h2));
    float x0 = expf(h0 - hm), x1 = expf(h1 - hm), x2 = expf(h2 - hm);
    float hinv = 1.0f / (x0 + x1 + x2);
    float mass = softplusf(L[g][4]) + 0.5f;
    int cls = 0;
    float best = L[g][5];
    for (int c = 1; c < 32; c++) {
      if (L[g][5 + c] > best) { best = L[g][5 + c]; cls = c; }
    }
    float* f = feat + (size_t)t * 8;
    f[0] = charge; f[1] = mass;
    f[2] = x0 * hinv; f[3] = x1 * hinv; f[4] = x2 * hinv;
    f[5] = (float)cls; f[6] = 0.0f; f[7] = 0.0f;
    float* sp_ = sw + (size_t)t * 4;
    sp_[0] = w0; sp_[1] = w1; sp_[2] = w2; sp_[3] = 0.0f;
  }
}

// ---------------------------------------------------------------------------
__global__ __launch_bounds__(256) void k_scores(
    const float* __restrict__ feat, const float* __restrict__ compat,
    const float* __restrict__ wchg, const float* __restrict__ wsh,
    const float* __restrict__ wdist, const float* __restrict__ wmass,
    const float* __restrict__ wval, const float* __restrict__ temp_p,
    bf16* __restrict__ P)
{
  const int i = blockIdx.x, b = blockIdx.y;
  const int tid = threadIdx.x;
  __shared__ float cs[1024];
  __shared__ float red[256];
  for (int k = tid; k < 1024; k += 256) cs[k] = compat[k];
  __syncthreads();

  const float a = softplusf(wchg[0]);
  const float bs = softplusf(wsh[0]);
  const float c = softplusf(wdist[0]);
  const float dm = softplusf(wmass[0]);
  const float ev = softplusf(wval[0]);
  const float itmp = 1.0f / softplusf(temp_p[0]);

  const float4* fi4 = (const float4*)(feat + ((size_t)b * 2048 + i) * 8);
  float4 fiA = fi4[0], fiB = fi4[1];
  const float ci = fiA.x, mi = fiA.y, si0 = fiA.z, si1 = fiA.w, si2 = fiB.x;
  int cli = (int)fiB.y; cli = cli < 0 ? 0 : (cli > 31 ? 31 : cli);

  float sc[8];
  float lmax = -3.0e38f;
#pragma unroll
  for (int jj = 0; jj < 8; jj++) {
    int j = tid + jj * 256;
    const float4* fj4 = (const float4*)(feat + ((size_t)b * 2048 + j) * 8);
    float4 fjA = fj4[0], fjB = fj4[1];
    int clj = (int)fjB.y; clj = clj < 0 ? 0 : (clj > 31 ? 31 : clj);
    float E = a * ci * fjA.x
            + bs * (fabsf(si0 - fjA.z) + fabsf(si1 - fjA.w) + fabsf(si2 - fjB.x))
            - c / (1.0f + 0.1f * fabsf((float)(i - j)))
            + dm * 0.1f * mi * fjA.y
            - ev;
    float s = (j <= i) ? (-E * itmp) * cs[cli * 32 + clj] : -3.0e38f;
    sc[jj] = s;
    lmax = fmaxf(lmax, s);
  }
  red[tid] = lmax;
  __syncthreads();
  for (int st = 128; st > 0; st >>= 1) {
    if (tid < st) red[tid] = fmaxf(red[tid], red[tid + st]);
    __syncthreads();
  }
  const float mrow = red[0];
  __syncthreads();

  float pv[8];
  float lsum = 0.0f;
#pragma unroll
  for (int jj = 0; jj < 8; jj++) {
    pv[jj] = (sc[jj] > -1.0e37f) ? expf(sc[jj] - mrow) : 0.0f;
    lsum += pv[jj];
  }
  red[tid] = lsum;
  __syncthreads();
  for (int st = 128; st > 0; st >>= 1) {
    if (tid < st) red[tid] += red[tid + st];
    __syncthreads();
  }
  const float inv = 1.0f / red[0];
  bf16* Pi = P + ((size_t)b * 2048 + i) * 2048;
#pragma unroll
  for (int jj = 0; jj < 8; jj++) Pi[tid + jj * 256] = f2bf(pv[jj] * inv);
}

// ---------------------------------------------------------------------------
extern "C" void kernel_launch(void* const* d_in, const int* in_sizes, int n_in,
                              void* d_out, int out_size, void* d_ws, size_t ws_size,
                              hipStream_t stream) {
  (void)in_sizes; (void)n_in; (void)out_size; (void)ws_size;
  const float* x        = (const float*)d_in[0];
  const float* W_sense  = (const float*)d_in[1];
  const float* b_sense  = (const float*)d_in[2];
  const float* W_ctx    = (const float*)d_in[3];
  const float* b_ctx    = (const float*)d_in[4];
  const float* W_sel    = (const float*)d_in[5];
  const float* b_sel    = (const float*)d_in[6];
  const float* W_charge = (const float*)d_in[7];
  const float* b_charge = (const float*)d_in[8];
  const float* W_shell  = (const float*)d_in[9];
  const float* b_shell  = (const float*)d_in[10];
  const float* W_class  = (const float*)d_in[11];
  const float* b_class  = (const float*)d_in[12];
  const float* W_mass   = (const float*)d_in[13];
  const float* b_mass   = (const float*)d_in[14];
  const float* compat_logits = (const float*)d_in[17];
  const float* w_charge = (const float*)d_in[18];
  const float* w_shell  = (const float*)d_in[19];
  const float* w_distance = (const float*)d_in[20];
  const float* w_mass   = (const float*)d_in[21];
  const float* w_valence = (const float*)d_in[22];
  const float* temperature = (const float*)d_in[23];
  const float* W_v      = (const float*)d_in[24];
  const float* b_v      = (const float*)d_in[25];
  const float* W_out    = (const float*)d_in[26];
  const float* b_out    = (const float*)d_in[27];

  char* w = (char*)d_ws;
  auto alloc = [&](size_t bytes) {
    char* p = w;
    w += (bytes + 255) & ~(size_t)255;
    return p;
  };
  bf16* xhhl  = (bf16*)alloc(8192ULL * 3072 * 2);
  char* R1    = alloc(48ULL * 1024 * 1024);
  bf16* Wsn3  = (bf16*)R1;
  float* Hh   = (float*)R1;
  float* Mtp  = (float*)(R1 + 20ULL * 1024 * 1024);      // [24][131072] fp32
  bf16* Mthl  = (bf16*)(R1 + 40ULL * 1024 * 1024);       // [512][3072] bf16
  float* Mt   = (float*)(R1 + 44ULL * 1024 * 1024);      // [3][128][1024] fp32
  bf16* y     = (bf16*)R1;                               // [8192][1024] bf16
  bf16* Wts2  = (bf16*)alloc(3072ULL * 1024 * 2);        // Bt2 [1024][3072]
  bf16* Wt_v  = (bf16*)alloc(1024ULL * 1024 * 2);
  bf16* Wt_out = (bf16*)alloc(1024ULL * 1024 * 2);
  bf16* Whhl3 = (bf16*)alloc(128ULL * 3072 * 2);
  float* bh   = (float*)alloc(3ULL * 128 * 4);
  float* bhead = (float*)alloc(256);
  float* csig = (float*)alloc(4096);
  float* xbar = (float*)alloc(4ULL * 1024 * 4);
  float* qbuf = (float*)alloc(1025ULL * 3 * 4);
  float* ctx_sel = (float*)alloc(256);
  float* feat = (float*)alloc(8192ULL * 8 * 4);
  float* sw   = (float*)alloc(8192ULL * 4 * 4);
  // aliases inside xhhl (48 MB flat); Vt/O written only after gemm_y is done
  bf16* Vt = xhhl + 8388608;          // 16 MB
  bf16* O  = xhhl + 16777216;         // 16 MB
  bf16* P  = (bf16*)d_out;            // 32 MiB; consumed before final GEMM

  // ---- input conversions ----
  k_split_x3<<<32768, 256, 0, stream>>>(x, xhhl);
  k_split_ws3<<<12288, 256, 0, stream>>>(W_sense, Wsn3);
  k_trans_sense<<<dim3(32, 32, 3), 256, 0, stream>>>(W_sense, Wts2);
  k_trans_hl<<<dim3(32, 32), 256, 0, stream>>>(W_v, Wt_v, 1024, 1024);
  k_trans_hl<<<dim3(32, 32), 256, 0, stream>>>(W_out, Wt_out, 1024, 1024);
  k_pack<<<128, 256, 0, stream>>>(W_charge, W_shell, W_class, W_mass,
                                  b_charge, b_shell, b_class, b_mass,
                                  compat_logits, Whhl3, bhead, csig);

  // ---- ctx path ----
  hipMemsetAsync(xbar, 0, 4096 * 4, stream);
  k_xbar<<<dim3(4, 4, 8), 256, 0, stream>>>(x, xbar);
  k_q<<<1025, 256, 0, stream>>>(W_ctx, b_ctx, W_sel, qbuf);
  k_ctxsel<<<4, 256, 0, stream>>>(xbar, qbuf, ctx_sel);

  // ---- Mt fold: 8-way K-split (chunk=384) -> 192 blocks, then reduce ----
  gemm_bt<1, 0, 0, 0, 8><<<dim3(8, 1, 24), 512, 0, stream>>>(
      Whhl3, Wsn3, nullptr, Mtp, 128, 1024, 384, 3072, 3072, 1024,
      0, 3145728L, 131072L);
  k_reduce_mt<<<1536, 256, 0, stream>>>(Mtp, Mt);
  k_split<<<6144, 256, 0, stream>>>(Mt, W_sel, Mthl);

  // ---- H = x @ [Mt | Wsel]^T, 2-way K-split (chunk=1536) -> 512 blocks ----
  gemm_bt<1, 0, 0, 1, 2><<<dim3(256, 1, 2), 512, 0, stream>>>(
      xhhl, Mthl, nullptr, Hh, 8192, 512, 1536, 3072, 3072, 512,
      0, 0, 4194304L);

  // ---- bh (exact fp32) + per-token heads (sums the 2 H planes) ----
  k_bh<<<dim3(37, 3), 256, 0, stream>>>(b_sense, W_charge, W_shell, W_class, W_mass, bh);
  k_heads<<<2048, 256, 0, stream>>>(Hh, ctx_sel, b_sel, bh, bhead, sw, feat);

  // ---- y = sum_s sw_s*(x @ W_sense_s) + sw-wtd bias (boundary-scaled) ----
  gemm_y<<<512, 512, 0, stream>>>(xhhl, Wts2, b_sense, sw, y);

  // ---- V^T (batched): Vt[b][d][n], LDS-transposed coalesced epilogue ----
  gemm_bt<2, 0, 0, 1><<<512, 512, 0, stream>>>(
      y, Wt_v, b_v, Vt, 8192, 1024, 1024, 1024, 1024, 0, 0, 0, 0);

  // ---- P = causal softmax of pair scores (in d_out) ----
  k_scores<<<dim3(2048, 4), 256, 0, stream>>>(feat, csig, w_charge, w_shell,
                                              w_distance, w_mass, w_valence, temperature, P);

  // ---- O = P @ V (causal k-limit, heavy-first), per batch ----
  gemm_bt<0, 1, 0, 0><<<dim3(8, 16, 4), 512, 0, stream>>>(
      P, Vt, nullptr, O, 2048, 1024, 2048, 2048, 2048, 1024,
      2048L * 2048, 1024L * 2048, 2048L * 1024);

  // ---- out = O @ W_out + b_out (fp32, overwrites P) ----
  gemm_bt<1, 0, 0, 1><<<512, 512, 0, stream>>>(
      O, Wt_out, b_out, (float*)d_out, 8192, 1024, 1024, 1024, 1024, 1024, 0, 0, 0);
}